// Round 1
// baseline (13001.894 us; speedup 1.0000x reference)
//
#include <hip/hip_runtime.h>
#include <hip/hip_cooperative_groups.h>
#include <math.h>

namespace cg = cooperative_groups;

#define NVERT 8192
#define NEDGE 65536
#define NBATCH 32
#define NSUB 8
#define NCG 20
#define GRID 256
#define BLOCK 1024
// GRID*BLOCK == NVERT*NBATCH exactly (262144): one thread per (vertex,batch) pair.

__device__ __forceinline__ float3 ld3(const float* p) { return make_float3(p[0], p[1], p[2]); }
__device__ __forceinline__ void st3(float* p, float3 v) { p[0] = v.x; p[1] = v.y; p[2] = v.z; }

struct Params {
  const float* action;   // [B][NE]
  const float* pos0;     // [B][NV][3]
  const float* vel0;     // [B][NV][3]
  const float* rest_len; // [NE]
  const float* mass;     // [NV]
  const int* edge_i;     // [NE]
  const int* edge_j;     // [NE]
  float* out;            // [B][NSUB][NV][3]
  // workspace arrays
  float* pos;            // [NV][32][3]
  float* r;              // [NV][32][3]
  float* pA;             // [NV][32][3]
  float* pB;             // [NV][32][3]
  float* Ap;             // [NV][32][3]
  float* rest_eff;       // [NE][32]
  int* adj_nbr;          // [2*NE]
  int* adj_edge;         // [2*NE]
  int* row_ptr;          // [NV+1]
  int* cursor;           // [NV]
  double* acc;           // [3][32] rotating dot-product slots
};

// block-reduce a per-thread double partial (per batch b = lane&31) and
// atomically add into acc slot (pub%3); block 0 zeroes slot (pub+1)%3 for
// the NEXT publish (that slot was last read one full pass ago -> safe).
__device__ __forceinline__ void publish(double* acc, int pub, double part, double* lds_dot) {
  const int slot = pub % 3, znext = (pub + 1) % 3;
  if (blockIdx.x == 0 && threadIdx.x < 32) acc[znext * 32 + threadIdx.x] = 0.0;
  part += __shfl_down(part, 32);  // lane L += lane L+32 (same batch, other vertex)
  const int lane = threadIdx.x & 63;
  const int w = threadIdx.x >> 6;
  if (lane < 32) lds_dot[w * 32 + lane] = part;
  __syncthreads();
  if (threadIdx.x < 32) {
    double s = 0.0;
#pragma unroll
    for (int ww = 0; ww < BLOCK / 64; ++ww) s += lds_dot[ww * 32 + threadIdx.x];
    unsafeAtomicAdd(&acc[slot * 32 + threadIdx.x], s);
  }
  __syncthreads();
}

__global__ void __launch_bounds__(BLOCK) mass_spring_kernel(Params P) {
  cg::grid_group grid = cg::this_grid();
  __shared__ double lds_dot[(BLOCK / 64) * 32];
  __shared__ int lds_scan[BLOCK];

  const int tid = threadIdx.x;
  const int gtid = blockIdx.x * BLOCK + tid;
  const int b = tid & 31;
  const int v = gtid >> 5;
  const int vi = (v * 32 + b) * 3;

  // ---------- setup: rest_eff, pos transpose-in, zero counters ----------
  for (int i = gtid; i < NEDGE * NBATCH; i += GRID * BLOCK) {
    const int e = i >> 5, bb = i & 31;
    P.rest_eff[e * 32 + bb] = P.rest_len[e] * (1.0f + P.action[bb * NEDGE + e]);
  }
#pragma unroll
  for (int c = 0; c < 3; ++c) P.pos[vi + c] = P.pos0[(b * NVERT + v) * 3 + c];
  float3 vv = make_float3(P.vel0[(b * NVERT + v) * 3 + 0],
                          P.vel0[(b * NVERT + v) * 3 + 1],
                          P.vel0[(b * NVERT + v) * 3 + 2]);
  if (gtid < NVERT) P.cursor[gtid] = 0;
  if (gtid < 96) P.acc[gtid] = 0.0;
  grid.sync();

  // degree histogram
  if (gtid < NEDGE) {
    atomicAdd(&P.cursor[P.edge_i[gtid]], 1);
    atomicAdd(&P.cursor[P.edge_j[gtid]], 1);
  }
  grid.sync();

  // exclusive scan (block 0): cursor(deg) -> row_ptr, cursor=row start
  if (blockIdx.x == 0) {
    const int base = tid * (NVERT / BLOCK);  // 8 per thread
    int loc[NVERT / BLOCK];
    int s8 = 0;
#pragma unroll
    for (int i = 0; i < NVERT / BLOCK; ++i) { loc[i] = P.cursor[base + i]; s8 += loc[i]; }
    lds_scan[tid] = s8;
    __syncthreads();
    for (int off = 1; off < BLOCK; off <<= 1) {
      int t = 0;
      if (tid >= off) t = lds_scan[tid - off];
      __syncthreads();
      if (tid >= off) lds_scan[tid] += t;
      __syncthreads();
    }
    int run = lds_scan[tid] - s8;  // exclusive prefix
#pragma unroll
    for (int i = 0; i < NVERT / BLOCK; ++i) {
      P.row_ptr[base + i] = run;
      P.cursor[base + i] = run;
      run += loc[i];
    }
    if (tid == BLOCK - 1) P.row_ptr[NVERT] = run;  // == 2*NE
  }
  grid.sync();

  // fill adjacency
  if (gtid < NEDGE) {
    const int ei = P.edge_i[gtid], ej = P.edge_j[gtid];
    const int ai = atomicAdd(&P.cursor[ei], 1);
    P.adj_nbr[ai] = ej; P.adj_edge[ai] = gtid;
    const int aj = atomicAdd(&P.cursor[ej], 1);
    P.adj_nbr[aj] = ei; P.adj_edge[aj] = gtid;
  }
  grid.sync();

  const float m_v = P.mass[v];
  const int rbeg = P.row_ptr[v];
  const int rend = P.row_ptr[v + 1];
  const float degf = (float)(rend - rbeg);

  float* pPrev = P.pA;
  float* pCur = P.pB;
  int pub = 0;

  float3 pv = ld3(P.pos + vi);  // register copy of own position

  for (int s = 0; s < NSUB; ++s) {
    // ---------- F: spring force + CG init (r = b, x = 0) ----------
    float fx = 0.f, fy = 0.f, fz = 0.f;
    for (int a = rbeg; a < rend; ++a) {
      const int u = P.adj_nbr[a];
      const int e = P.adj_edge[a];
      const float3 pu = ld3(P.pos + (u * 32 + b) * 3);
      const float dx = pv.x - pu.x, dy = pv.y - pu.y, dz = pv.z - pu.z;
      const float l = sqrtf(dx * dx + dy * dy + dz * dz);
      const float coef = -10000.0f * (l - P.rest_eff[e * 32 + b]) / fmaxf(l, 1e-6f);
      fx += coef * dx; fy += coef * dy; fz += coef * dz;
    }
    float3 rv;  // r_0 = b = m*vel + DT*(f_spring + m*g)
    rv.x = m_v * vv.x + 0.01f * fx;
    rv.y = m_v * vv.y + 0.01f * (fy - 9.8f * m_v);
    rv.z = m_v * vv.z + 0.01f * fz;
    st3(P.r + vi, rv);
    float3 xacc = make_float3(0.f, 0.f, 0.f);
    float3 pc = rv;  // will hold p_k in registers
    publish(P.acc, pub,
            (double)(rv.x * rv.x) + (double)(rv.y * rv.y) + (double)(rv.z * rv.z),
            lds_dot);
    ++pub;
    grid.sync();

    double rs_prev = 0.0;
    for (int k = 0; k < NCG; ++k) {
      const double rs_k = P.acc[((pub + 2) % 3) * 32 + b];
      const float beta = (k == 0) ? 0.0f : (float)(rs_k / (rs_prev + 1e-12));
      // ---------- M: p_k = r_k + beta*p_{k-1}; Ap = A p_k; dot(p,Ap) ----------
      float sx = 0.f, sy = 0.f, sz = 0.f;  // sum of p_k over neighbors
      if (k == 0) {
        pc = rv;  // p_0 = r_0
        for (int a = rbeg; a < rend; ++a) {
          const int u = P.adj_nbr[a];
          const float3 ru = ld3(P.r + (u * 32 + b) * 3);
          sx += ru.x; sy += ru.y; sz += ru.z;
        }
      } else {
        pc.x = rv.x + beta * pc.x;
        pc.y = rv.y + beta * pc.y;
        pc.z = rv.z + beta * pc.z;
        for (int a = rbeg; a < rend; ++a) {
          const int u = P.adj_nbr[a];
          const int o = (u * 32 + b) * 3;
          const float3 ru = ld3(P.r + o);
          const float3 pu = ld3(pPrev + o);
          sx += ru.x + beta * pu.x;
          sy += ru.y + beta * pu.y;
          sz += ru.z + beta * pu.z;
        }
      }
      st3(pCur + vi, pc);
      float3 ap;  // A p = m*p + DT^2*K*(deg*p - sum_nbr p); DT^2*K == 1.0f
      ap.x = m_v * pc.x + (degf * pc.x - sx);
      ap.y = m_v * pc.y + (degf * pc.y - sy);
      ap.z = m_v * pc.z + (degf * pc.z - sz);
      st3(P.Ap + vi, ap);
      publish(P.acc, pub,
              (double)(pc.x * ap.x) + (double)(pc.y * ap.y) + (double)(pc.z * ap.z),
              lds_dot);
      ++pub;
      grid.sync();
      const double pAp = P.acc[((pub + 2) % 3) * 32 + b];
      const float alpha = (float)(rs_k / (pAp + 1e-12));
      // ---------- U: x += alpha p; r -= alpha Ap; dot(r,r) ----------
      xacc.x += alpha * pc.x; xacc.y += alpha * pc.y; xacc.z += alpha * pc.z;
      rv.x -= alpha * ap.x; rv.y -= alpha * ap.y; rv.z -= alpha * ap.z;
      st3(P.r + vi, rv);
      publish(P.acc, pub,
              (double)(rv.x * rv.x) + (double)(rv.y * rv.y) + (double)(rv.z * rv.z),
              lds_dot);
      ++pub;
      grid.sync();
      rs_prev = rs_k;
      float* t = pPrev; pPrev = pCur; pCur = t;
    }

    // ---------- W: pos += DT*v_new; vel = v_new; write trajectory ----------
    pv.x += 0.01f * xacc.x;
    pv.y += 0.01f * xacc.y;
    pv.z += 0.01f * xacc.z;
    st3(P.pos + vi, pv);
    vv = xacc;
    float* o = P.out + ((size_t)(b * NSUB + s) * NVERT + (size_t)v) * 3;
    o[0] = pv.x; o[1] = pv.y; o[2] = pv.z;
    grid.sync();
  }
}

extern "C" void kernel_launch(void* const* d_in, const int* in_sizes, int n_in,
                              void* d_out, int out_size, void* d_ws, size_t ws_size,
                              hipStream_t stream) {
  Params P;
  P.action = (const float*)d_in[0];
  P.pos0 = (const float*)d_in[1];
  P.vel0 = (const float*)d_in[2];
  P.rest_len = (const float*)d_in[3];
  P.mass = (const float*)d_in[4];
  P.edge_i = (const int*)d_in[5];
  P.edge_j = (const int*)d_in[6];
  P.out = (float*)d_out;

  char* w = (char*)d_ws;
  auto alloc = [&](size_t bytes) {
    char* p = w;
    w += (bytes + 255) & ~(size_t)255;
    return p;
  };
  const size_t vec_bytes = (size_t)NVERT * NBATCH * 3 * sizeof(float);  // 3.15 MB
  P.pos      = (float*)alloc(vec_bytes);
  P.r        = (float*)alloc(vec_bytes);
  P.pA       = (float*)alloc(vec_bytes);
  P.pB       = (float*)alloc(vec_bytes);
  P.Ap       = (float*)alloc(vec_bytes);
  P.rest_eff = (float*)alloc((size_t)NEDGE * NBATCH * sizeof(float));   // 8.4 MB
  P.adj_nbr  = (int*)alloc((size_t)2 * NEDGE * sizeof(int));
  P.adj_edge = (int*)alloc((size_t)2 * NEDGE * sizeof(int));
  P.row_ptr  = (int*)alloc((size_t)(NVERT + 1) * sizeof(int));
  P.cursor   = (int*)alloc((size_t)NVERT * sizeof(int));
  P.acc      = (double*)alloc((size_t)3 * 32 * sizeof(double));

  void* args[] = { &P };
  hipLaunchCooperativeKernel(reinterpret_cast<void*>(mass_spring_kernel),
                             dim3(GRID), dim3(BLOCK), args, 0, stream);
}

// Round 4
// 9642.494 us; speedup vs baseline: 1.3484x; 1.3484x over previous
//
#include <hip/hip_runtime.h>
#include <hip/hip_cooperative_groups.h>
#include <math.h>

namespace cg = cooperative_groups;

#define NVERT 8192
#define NEDGE 65536
#define NSUB 8
#define NCG 20
#define GRID 256
#define BLOCK 1024
#define DT 0.01f
#define KS 10000.0f
// GRID*BLOCK == NVERT*32 (262144): one thread per (vertex,batch).
// 256x1024 is the EMPIRICALLY VALID cooperative geometry on this runtime
// (R0 ran; 512x512 failed to launch twice, even with launch_bounds(512,4)).
// 1024-thread blocks force VGPR<=128 so 1 block/CU co-residency always holds.

struct Params {
  const float* action;   // [B][NE]
  const float* pos0;     // [B][NV][3]
  const float* vel0;     // [B][NV][3]
  const float* rest_len; // [NE]
  const float* mass;     // [NV]
  const int* edge_i;     // [NE]
  const int* edge_j;     // [NE]
  float* out;            // [B][NSUB][NV][3]
  // workspace (vec arrays padded to float4: [NV][32] float4, 4 MB each)
  float4* pos;
  float4 *R0, *R1, *P0, *P1, *Q0, *Q1;  // r, p, Ap double-buffered
  float* rest_eff;       // [NE][32]
  int* adj_off;          // [2NE] neighbor vertex byte offset (u*512)
  int* adjE_off;         // [2NE] edge byte offset into rest_eff (e*128)
  int* row_ptr;          // [NV+1]
  int* cursor;           // [NV]
  double* acc;           // [3 slots][3 quantities][32 batches]
};

__device__ __forceinline__ float4 f4(float3 a) { return make_float4(a.x, a.y, a.z, 0.f); }

// Publish 3 per-batch doubles (rs, pAp, ApAp) into rotating slot pub%3.
// Block 0 zeroes slot (pub+1)%3 for the next publish (that slot was last
// read a full phase ago, separated by grid.sync -> race-free).
__device__ __forceinline__ void publish3(double* acc, int pub, double d0, double d1,
                                         double d2, double* lds) {
  const int slot = pub % 3, zn = (pub + 1) % 3;
  if (blockIdx.x == 0 && threadIdx.x < 96) acc[zn * 96 + threadIdx.x] = 0.0;
  d0 += __shfl_down(d0, 32);  // lane L += lane L+32: same batch, paired vertex
  d1 += __shfl_down(d1, 32);
  d2 += __shfl_down(d2, 32);
  const int lane = threadIdx.x & 63, w = threadIdx.x >> 6;
  if (lane < 32) {
    lds[w * 96 + lane] = d0;
    lds[w * 96 + 32 + lane] = d1;
    lds[w * 96 + 64 + lane] = d2;
  }
  __syncthreads();
  if (threadIdx.x < 96) {
    double s = 0.0;
#pragma unroll
    for (int ww = 0; ww < BLOCK / 64; ++ww) s += lds[ww * 96 + threadIdx.x];
    unsafeAtomicAdd(&acc[slot * 96 + threadIdx.x], s);
  }
  __syncthreads();
}

__global__ void __launch_bounds__(BLOCK) mass_spring_kernel(Params P) {
  cg::grid_group grid = cg::this_grid();
  __shared__ double lds_red[(BLOCK / 64) * 96];
  __shared__ int lds_scan[BLOCK];

  const int tid = threadIdx.x;
  const int gtid = blockIdx.x * BLOCK + tid;
  const int b = tid & 31;
  const int v = gtid >> 5;
  const int vb = v * 32 + b;
  const int b16 = b * 16, b4 = b * 4;

  // ---------- setup ----------
  for (int i = gtid; i < NEDGE * 32; i += GRID * BLOCK) {
    const int e = i >> 5, bb = i & 31;
    P.rest_eff[e * 32 + bb] = P.rest_len[e] * (1.0f + P.action[bb * NEDGE + e]);
  }
  float3 pv, vv;
  pv.x = P.pos0[(b * NVERT + v) * 3 + 0];
  pv.y = P.pos0[(b * NVERT + v) * 3 + 1];
  pv.z = P.pos0[(b * NVERT + v) * 3 + 2];
  vv.x = P.vel0[(b * NVERT + v) * 3 + 0];
  vv.y = P.vel0[(b * NVERT + v) * 3 + 1];
  vv.z = P.vel0[(b * NVERT + v) * 3 + 2];
  P.pos[vb] = f4(pv);
  if (gtid < NVERT) P.cursor[gtid] = 0;
  if (gtid < 288) P.acc[gtid] = 0.0;
  grid.sync();

  if (gtid < NEDGE) {
    atomicAdd(&P.cursor[P.edge_i[gtid]], 1);
    atomicAdd(&P.cursor[P.edge_j[gtid]], 1);
  }
  grid.sync();

  if (blockIdx.x == 0) {  // exclusive scan of degrees, 8 per thread
    const int base = tid * (NVERT / BLOCK);
    int loc[NVERT / BLOCK];
    int sum = 0;
#pragma unroll
    for (int i = 0; i < NVERT / BLOCK; ++i) { loc[i] = P.cursor[base + i]; sum += loc[i]; }
    lds_scan[tid] = sum;
    __syncthreads();
    for (int off = 1; off < BLOCK; off <<= 1) {
      int t = 0;
      if (tid >= off) t = lds_scan[tid - off];
      __syncthreads();
      if (tid >= off) lds_scan[tid] += t;
      __syncthreads();
    }
    int run = lds_scan[tid] - sum;
#pragma unroll
    for (int i = 0; i < NVERT / BLOCK; ++i) {
      P.row_ptr[base + i] = run;
      P.cursor[base + i] = run;
      run += loc[i];
    }
    if (tid == BLOCK - 1) P.row_ptr[NVERT] = run;
  }
  grid.sync();

  if (gtid < NEDGE) {  // fill adjacency as precomputed byte offsets
    const int ei = P.edge_i[gtid], ej = P.edge_j[gtid];
    const int ai = atomicAdd(&P.cursor[ei], 1);
    P.adj_off[ai] = ej * 512; P.adjE_off[ai] = gtid * 128;
    const int aj = atomicAdd(&P.cursor[ej], 1);
    P.adj_off[aj] = ei * 512; P.adjE_off[aj] = gtid * 128;
  }
  grid.sync();

  const float m_v = P.mass[v];
  const int rbeg = P.row_ptr[v], rend = P.row_ptr[v + 1];
  const float degf = (float)(rend - rbeg);

  float4* rRd = P.R0; float4* rWr = P.R1;
  float4* pRd = P.P0; float4* pWr = P.P1;
  float4* qRd = P.Q0; float4* qWr = P.Q1;
  int pub = 0;

  for (int s = 0; s < NSUB; ++s) {
    // ---------- F: spring force, r0 = b ----------
    float fx = 0.f, fy = 0.f, fz = 0.f;
    for (int a = rbeg; a < rend; ++a) {
      const int off = P.adj_off[a];
      const float4 pu = *(const float4*)((const char*)P.pos + off + b16);
      const float re = *(const float*)((const char*)P.rest_eff + P.adjE_off[a] + b4);
      const float dx = pv.x - pu.x, dy = pv.y - pu.y, dz = pv.z - pu.z;
      const float l = sqrtf(dx * dx + dy * dy + dz * dz);
      const float coef = -KS * (l - re) / fmaxf(l, 1e-6f);
      fx += coef * dx; fy += coef * dy; fz += coef * dz;
    }
    float3 rv;
    rv.x = m_v * vv.x + DT * fx;
    rv.y = m_v * vv.y + DT * (fy - 9.8f * m_v);
    rv.z = m_v * vv.z + DT * fz;
    rRd[vb] = f4(rv);  // r0 visible for phase-0 gather
    float3 xacc = make_float3(0.f, 0.f, 0.f);
    float3 pc = rv;    // p_k in registers
    float3 ap;         // Ap_k in registers
    grid.sync();

    // ---------- pipelined CG: ONE grid.sync per iteration ----------
    for (int k = 0; k < NCG; ++k) {
      if (k == 0) {
        float sx = 0.f, sy = 0.f, sz = 0.f;
#pragma unroll 2
        for (int a = rbeg; a < rend; ++a) {
          const int off = P.adj_off[a];
          const float4 ru = *(const float4*)((const char*)rRd + off + b16);
          sx += ru.x; sy += ru.y; sz += ru.z;
        }
        ap.x = m_v * pc.x + degf * pc.x - sx;
        ap.y = m_v * pc.y + degf * pc.y - sy;
        ap.z = m_v * pc.z + degf * pc.z - sz;
        rWr[vb] = f4(rv);  // forward r0 into the ping-pong chain
      } else {
        const int ps = (pub + 2) % 3;  // slot published last phase
        const double rsx = P.acc[ps * 96 + b];        // rs_{k-1} (exact)
        const double pq  = P.acc[ps * 96 + 32 + b];   // p.Ap_{k-1}
        const double qq  = P.acc[ps * 96 + 64 + b];   // Ap.Ap_{k-1}
        const float alpha = (float)(rsx / (pq + 1e-12));
        const double rs_rec = (double)alpha * (double)alpha * qq - rsx;  // rs_k
        const float beta = (float)(rs_rec / (rsx + 1e-12));
        xacc.x += alpha * pc.x; xacc.y += alpha * pc.y; xacc.z += alpha * pc.z;
        rv.x -= alpha * ap.x; rv.y -= alpha * ap.y; rv.z -= alpha * ap.z;
        rWr[vb] = f4(rv);
        pc.x = rv.x + beta * pc.x; pc.y = rv.y + beta * pc.y; pc.z = rv.z + beta * pc.z;
        float sx = 0.f, sy = 0.f, sz = 0.f;
#pragma unroll 2
        for (int a = rbeg; a < rend; ++a) {
          const int off = P.adj_off[a];
          const float4 ru = *(const float4*)((const char*)rRd + off + b16);
          const float4 pu = *(const float4*)((const char*)pRd + off + b16);
          const float4 qu = *(const float4*)((const char*)qRd + off + b16);
          // p_k[u] = (r_{k-1}[u] - alpha*Ap_{k-1}[u]) + beta*p_{k-1}[u]
          sx += ru.x - alpha * qu.x + beta * pu.x;
          sy += ru.y - alpha * qu.y + beta * pu.y;
          sz += ru.z - alpha * qu.z + beta * pu.z;
        }
        ap.x = m_v * pc.x + degf * pc.x - sx;
        ap.y = m_v * pc.y + degf * pc.y - sy;
        ap.z = m_v * pc.z + degf * pc.z - sz;
      }
      pWr[vb] = f4(pc);
      qWr[vb] = f4(ap);
      const double rs_part = (double)(rv.x * rv.x) + (double)(rv.y * rv.y) + (double)(rv.z * rv.z);
      const double pq_part = (double)(pc.x * ap.x) + (double)(pc.y * ap.y) + (double)(pc.z * ap.z);
      const double qq_part = (double)(ap.x * ap.x) + (double)(ap.y * ap.y) + (double)(ap.z * ap.z);
      publish3(P.acc, pub, rs_part, pq_part, qq_part, lds_red);
      ++pub;
      float4* t;
      t = rRd; rRd = rWr; rWr = t;
      t = pRd; pRd = pWr; pWr = t;
      t = qRd; qRd = qWr; qWr = t;
      grid.sync();
    }

    // ---------- W: final alpha, integrate, write out ----------
    {
      const int ps = (pub + 2) % 3;
      const double rsx = P.acc[ps * 96 + b];
      const double pq  = P.acc[ps * 96 + 32 + b];
      const float alpha = (float)(rsx / (pq + 1e-12));
      xacc.x += alpha * pc.x; xacc.y += alpha * pc.y; xacc.z += alpha * pc.z;
      vv = xacc;
      pv.x += DT * vv.x; pv.y += DT * vv.y; pv.z += DT * vv.z;
      P.pos[vb] = f4(pv);
      float* o = P.out + ((size_t)(b * NSUB + s) * NVERT + (size_t)v) * 3;
      o[0] = pv.x; o[1] = pv.y; o[2] = pv.z;
      grid.sync();
    }
  }
}

extern "C" void kernel_launch(void* const* d_in, const int* in_sizes, int n_in,
                              void* d_out, int out_size, void* d_ws, size_t ws_size,
                              hipStream_t stream) {
  Params P;
  P.action = (const float*)d_in[0];
  P.pos0 = (const float*)d_in[1];
  P.vel0 = (const float*)d_in[2];
  P.rest_len = (const float*)d_in[3];
  P.mass = (const float*)d_in[4];
  P.edge_i = (const int*)d_in[5];
  P.edge_j = (const int*)d_in[6];
  P.out = (float*)d_out;

  char* w = (char*)d_ws;
  auto alloc = [&](size_t bytes) {
    char* p = w;
    w += (bytes + 255) & ~(size_t)255;
    return p;
  };
  const size_t vec_bytes = (size_t)NVERT * 32 * sizeof(float4);  // 4 MB
  P.pos = (float4*)alloc(vec_bytes);
  P.R0 = (float4*)alloc(vec_bytes);
  P.R1 = (float4*)alloc(vec_bytes);
  P.P0 = (float4*)alloc(vec_bytes);
  P.P1 = (float4*)alloc(vec_bytes);
  P.Q0 = (float4*)alloc(vec_bytes);
  P.Q1 = (float4*)alloc(vec_bytes);
  P.rest_eff = (float*)alloc((size_t)NEDGE * 32 * sizeof(float));
  P.adj_off  = (int*)alloc((size_t)2 * NEDGE * sizeof(int));
  P.adjE_off = (int*)alloc((size_t)2 * NEDGE * sizeof(int));
  P.row_ptr  = (int*)alloc((size_t)(NVERT + 1) * sizeof(int));
  P.cursor   = (int*)alloc((size_t)NVERT * sizeof(int));
  P.acc      = (double*)alloc((size_t)3 * 96 * sizeof(double));

  void* args[] = { &P };
  hipLaunchCooperativeKernel(reinterpret_cast<void*>(mass_spring_kernel),
                             dim3(GRID), dim3(BLOCK), args, 0, stream);
}

// Round 5
// 7777.436 us; speedup vs baseline: 1.6717x; 1.2398x over previous
//
#include <hip/hip_runtime.h>
#include <hip/hip_cooperative_groups.h>
#include <math.h>

namespace cg = cooperative_groups;

#define NVERT 8192
#define NEDGE 65536
#define NSUB 8
#define NCG 20
#define GRID 256
#define BLOCK 1024
#define DT 0.01f
#define KS 10000.0f
// 256x1024 is the EMPIRICALLY VALID cooperative geometry (512x512 failed to
// launch twice). 1024-thread blocks cap VGPR<=128 -> co-residency guaranteed.
//
// R4 core change: neighbor-sum recurrences. S_r = sum_u r[u], S_p = sum_u p[u]
// obey S_r -= alpha*S_q ; S_p = S_r + beta*S_p where S_q = sum_u Ap[u] is the
// ONLY gathered quantity (1 array/iteration instead of 3). Reductions via
// store+re-reduce (no 256-way atomic chains).

struct Params {
  const float* action;   // [B][NE]
  const float* pos0;     // [B][NV][3]
  const float* vel0;     // [B][NV][3]
  const float* rest_len; // [NE]
  const float* mass;     // [NV]
  const int* edge_i;     // [NE]
  const int* edge_j;     // [NE]
  float* out;            // [B][NSUB][NV][3]
  float4* pos;           // [NV*32]
  float4* Q0;            // ping-pong: holds r0 (k=0) or Ap_{k-1}
  float4* Q1;
  float* rest_eff;       // [NE][32]
  int* adj_off;          // [2NE] neighbor vertex byte offset (u*512)
  int* adjE_off;         // [2NE] edge byte offset into rest_eff (e*128)
  int* row_ptr;          // [NV+1]
  int* cursor;           // [NV]
  double* Pd;            // [2 parity][96][256] per-block partials
};

__device__ __forceinline__ float4 f4(float3 a) { return make_float4(a.x, a.y, a.z, 0.f); }

// End-of-phase publish: block partial of 3 per-batch doubles -> Pd[par][q][blk].
// No atomics; consumed by reduce_in() next phase (separated by grid.sync).
__device__ __forceinline__ void publish_store(double* Pd, int par, double d0, double d1,
                                              double d2, double* lds) {
  d0 += __shfl_down(d0, 32);  // lane L += L+32: same batch, paired vertex
  d1 += __shfl_down(d1, 32);
  d2 += __shfl_down(d2, 32);
  const int lane = threadIdx.x & 63, w = threadIdx.x >> 6;
  if (lane < 32) {
    lds[w * 96 + lane] = d0;
    lds[w * 96 + 32 + lane] = d1;
    lds[w * 96 + 64 + lane] = d2;
  }
  __syncthreads();
  if (threadIdx.x < 96) {
    double s = 0.0;
#pragma unroll
    for (int ww = 0; ww < BLOCK / 64; ++ww) s += lds[ww * 96 + threadIdx.x];
    Pd[(size_t)par * 96 * 256 + (size_t)threadIdx.x * 256 + blockIdx.x] = s;
  }
  __syncthreads();
}

// Start-of-phase reduce: sum Pd[par][q][0..255] -> lds_acc[q] (deterministic).
__device__ __forceinline__ void reduce_in(const double* Pd, int par,
                                          double* lds_part, double* lds_acc) {
  const int tid = threadIdx.x;
  const int q = tid >> 3, c = tid & 7;
  if (q < 96) {
    const double* src = Pd + (size_t)par * 96 * 256 + (size_t)q * 256 + c * 32;
    double s = 0.0;
#pragma unroll
    for (int i = 0; i < 32; ++i) s += src[i];
    lds_part[q * 8 + c] = s;
  }
  __syncthreads();
  if (tid < 96) {
    double s = 0.0;
#pragma unroll
    for (int c2 = 0; c2 < 8; ++c2) s += lds_part[tid * 8 + c2];
    lds_acc[tid] = s;
  }
  __syncthreads();
}

__global__ void __launch_bounds__(BLOCK) mass_spring_kernel(Params P) {
  cg::grid_group grid = cg::this_grid();
  __shared__ double lds_red[(BLOCK / 64) * 96];  // 12 KB
  __shared__ double lds_part[96 * 8];            // 6 KB
  __shared__ double lds_acc[96];                 // 768 B
  __shared__ int lds_scan[BLOCK];                // 4 KB

  const int tid = threadIdx.x;
  const int gtid = blockIdx.x * BLOCK + tid;
  const int b = tid & 31;
  const int v = gtid >> 5;
  const int vb = v * 32 + b;
  const int b16 = b * 16, b4 = b * 4;

  // ---------- setup ----------
  for (int i = gtid; i < NEDGE * 32; i += GRID * BLOCK) {
    const int e = i >> 5, bb = i & 31;
    P.rest_eff[e * 32 + bb] = P.rest_len[e] * (1.0f + P.action[bb * NEDGE + e]);
  }
  float3 pv, vv;
  pv.x = P.pos0[(b * NVERT + v) * 3 + 0];
  pv.y = P.pos0[(b * NVERT + v) * 3 + 1];
  pv.z = P.pos0[(b * NVERT + v) * 3 + 2];
  vv.x = P.vel0[(b * NVERT + v) * 3 + 0];
  vv.y = P.vel0[(b * NVERT + v) * 3 + 1];
  vv.z = P.vel0[(b * NVERT + v) * 3 + 2];
  P.pos[vb] = f4(pv);
  if (gtid < NVERT) P.cursor[gtid] = 0;
  grid.sync();

  if (gtid < NEDGE) {
    atomicAdd(&P.cursor[P.edge_i[gtid]], 1);
    atomicAdd(&P.cursor[P.edge_j[gtid]], 1);
  }
  grid.sync();

  if (blockIdx.x == 0) {  // exclusive scan of degrees, 8 per thread
    const int base = tid * (NVERT / BLOCK);
    int loc[NVERT / BLOCK];
    int sum = 0;
#pragma unroll
    for (int i = 0; i < NVERT / BLOCK; ++i) { loc[i] = P.cursor[base + i]; sum += loc[i]; }
    lds_scan[tid] = sum;
    __syncthreads();
    for (int off = 1; off < BLOCK; off <<= 1) {
      int t = 0;
      if (tid >= off) t = lds_scan[tid - off];
      __syncthreads();
      if (tid >= off) lds_scan[tid] += t;
      __syncthreads();
    }
    int run = lds_scan[tid] - sum;
#pragma unroll
    for (int i = 0; i < NVERT / BLOCK; ++i) {
      P.row_ptr[base + i] = run;
      P.cursor[base + i] = run;
      run += loc[i];
    }
    if (tid == BLOCK - 1) P.row_ptr[NVERT] = run;
  }
  grid.sync();

  if (gtid < NEDGE) {  // adjacency as precomputed byte offsets
    const int ei = P.edge_i[gtid], ej = P.edge_j[gtid];
    const int ai = atomicAdd(&P.cursor[ei], 1);
    P.adj_off[ai] = ej * 512; P.adjE_off[ai] = gtid * 128;
    const int aj = atomicAdd(&P.cursor[ej], 1);
    P.adj_off[aj] = ei * 512; P.adjE_off[aj] = gtid * 128;
  }
  grid.sync();

  const float m_v = P.mass[v];
  const int rbeg = P.row_ptr[v], rend = P.row_ptr[v + 1];
  const float degf = (float)(rend - rbeg);

  float4* qRd = P.Q0;
  float4* qWr = P.Q1;
  int pub = 0;  // publish counter; parity = pub & 1

  for (int s = 0; s < NSUB; ++s) {
    // ---------- F: spring force; write r0 into qRd for k=0's gather ----------
    float fx = 0.f, fy = 0.f, fz = 0.f;
    for (int a = rbeg; a < rend; ++a) {
      const int off = P.adj_off[a];
      const float4 pu = *(const float4*)((const char*)P.pos + off + b16);
      const float re = *(const float*)((const char*)P.rest_eff + P.adjE_off[a] + b4);
      const float dx = pv.x - pu.x, dy = pv.y - pu.y, dz = pv.z - pu.z;
      const float l = sqrtf(dx * dx + dy * dy + dz * dz);
      const float coef = -KS * (l - re) / fmaxf(l, 1e-6f);
      fx += coef * dx; fy += coef * dy; fz += coef * dz;
    }
    float3 rv;
    rv.x = m_v * vv.x + DT * fx;
    rv.y = m_v * vv.y + DT * (fy - 9.8f * m_v);
    rv.z = m_v * vv.z + DT * fz;
    qRd[vb] = f4(rv);  // r0 staged for k=0 gather
    float3 xacc = make_float3(0.f, 0.f, 0.f);
    float3 pc = rv;                 // p_k (registers)
    float3 ap;                      // Ap_k (registers)
    float3 Sr, Sp;                  // neighbor sums of r_k, p_k (registers)
    grid.sync();

    // ---------- CG: one grid.sync per iteration, 1-array gather ----------
    for (int k = 0; k < NCG; ++k) {
      if (k == 0) {
        float sx = 0.f, sy = 0.f, sz = 0.f;  // sum r0[u]
#pragma unroll 4
        for (int a = rbeg; a < rend; ++a) {
          const float4 qu = *(const float4*)((const char*)qRd + P.adj_off[a] + b16);
          sx += qu.x; sy += qu.y; sz += qu.z;
        }
        Sr = make_float3(sx, sy, sz);
        Sp = Sr;  // p0 = r0
        ap.x = (m_v + degf) * pc.x - Sp.x;
        ap.y = (m_v + degf) * pc.y - Sp.y;
        ap.z = (m_v + degf) * pc.z - Sp.z;
      } else {
        // overlap: gather S_q = sum Ap_{k-1}[u] while reducing partials
        float sx = 0.f, sy = 0.f, sz = 0.f;
#pragma unroll 4
        for (int a = rbeg; a < rend; ++a) {
          const float4 qu = *(const float4*)((const char*)qRd + P.adj_off[a] + b16);
          sx += qu.x; sy += qu.y; sz += qu.z;
        }
        reduce_in(P.Pd, (pub + 1) & 1, lds_part, lds_acc);  // (pub-1)&1
        const double rsx = lds_acc[b];        // |r_{k-1}|^2 (exact)
        const double pq  = lds_acc[32 + b];   // p.Ap
        const double qq  = lds_acc[64 + b];   // Ap.Ap
        const float alpha = (float)(rsx / (pq + 1e-12));
        const double rs_rec = (double)alpha * (double)alpha * qq - rsx;
        const float beta = (float)(rs_rec / (rsx + 1e-12));
        xacc.x += alpha * pc.x; xacc.y += alpha * pc.y; xacc.z += alpha * pc.z;
        rv.x -= alpha * ap.x; rv.y -= alpha * ap.y; rv.z -= alpha * ap.z;
        Sr.x -= alpha * sx; Sr.y -= alpha * sy; Sr.z -= alpha * sz;
        pc.x = rv.x + beta * pc.x; pc.y = rv.y + beta * pc.y; pc.z = rv.z + beta * pc.z;
        Sp.x = Sr.x + beta * Sp.x; Sp.y = Sr.y + beta * Sp.y; Sp.z = Sr.z + beta * Sp.z;
        ap.x = (m_v + degf) * pc.x - Sp.x;
        ap.y = (m_v + degf) * pc.y - Sp.y;
        ap.z = (m_v + degf) * pc.z - Sp.z;
      }
      qWr[vb] = f4(ap);
      publish_store(P.Pd, pub & 1,
                    (double)(rv.x * rv.x) + (double)(rv.y * rv.y) + (double)(rv.z * rv.z),
                    (double)(pc.x * ap.x) + (double)(pc.y * ap.y) + (double)(pc.z * ap.z),
                    (double)(ap.x * ap.x) + (double)(ap.y * ap.y) + (double)(ap.z * ap.z),
                    lds_red);
      ++pub;
      float4* t = qRd; qRd = qWr; qWr = t;
      grid.sync();
    }

    // ---------- W: final alpha, integrate, write out ----------
    {
      reduce_in(P.Pd, (pub + 1) & 1, lds_part, lds_acc);
      const double rsx = lds_acc[b];
      const double pq  = lds_acc[32 + b];
      const float alpha = (float)(rsx / (pq + 1e-12));
      xacc.x += alpha * pc.x; xacc.y += alpha * pc.y; xacc.z += alpha * pc.z;
      vv = xacc;
      pv.x += DT * vv.x; pv.y += DT * vv.y; pv.z += DT * vv.z;
      P.pos[vb] = f4(pv);
      float* o = P.out + ((size_t)(b * NSUB + s) * NVERT + (size_t)v) * 3;
      o[0] = pv.x; o[1] = pv.y; o[2] = pv.z;
      grid.sync();
    }
  }
}

extern "C" void kernel_launch(void* const* d_in, const int* in_sizes, int n_in,
                              void* d_out, int out_size, void* d_ws, size_t ws_size,
                              hipStream_t stream) {
  Params P;
  P.action = (const float*)d_in[0];
  P.pos0 = (const float*)d_in[1];
  P.vel0 = (const float*)d_in[2];
  P.rest_len = (const float*)d_in[3];
  P.mass = (const float*)d_in[4];
  P.edge_i = (const int*)d_in[5];
  P.edge_j = (const int*)d_in[6];
  P.out = (float*)d_out;

  char* w = (char*)d_ws;
  auto alloc = [&](size_t bytes) {
    char* p = w;
    w += (bytes + 255) & ~(size_t)255;
    return p;
  };
  const size_t vec_bytes = (size_t)NVERT * 32 * sizeof(float4);  // 4 MB
  P.pos = (float4*)alloc(vec_bytes);
  P.Q0  = (float4*)alloc(vec_bytes);
  P.Q1  = (float4*)alloc(vec_bytes);
  P.rest_eff = (float*)alloc((size_t)NEDGE * 32 * sizeof(float));
  P.adj_off  = (int*)alloc((size_t)2 * NEDGE * sizeof(int));
  P.adjE_off = (int*)alloc((size_t)2 * NEDGE * sizeof(int));
  P.row_ptr  = (int*)alloc((size_t)(NVERT + 1) * sizeof(int));
  P.cursor   = (int*)alloc((size_t)NVERT * sizeof(int));
  P.Pd       = (double*)alloc((size_t)2 * 96 * 256 * sizeof(double));

  void* args[] = { &P };
  hipLaunchCooperativeKernel(reinterpret_cast<void*>(mass_spring_kernel),
                             dim3(GRID), dim3(BLOCK), args, 0, stream);
}

// Round 6
// 6629.411 us; speedup vs baseline: 1.9612x; 1.1732x over previous
//
#include <hip/hip_runtime.h>
#include <hip/hip_cooperative_groups.h>
#include <math.h>

namespace cg = cooperative_groups;

#define NVERT 8192
#define NEDGE 65536
#define NSUB 8
#define NCG 20
#define GRID 256
#define BLOCK 1024
#define DT 0.01f
#define KS 10000.0f
// 256x1024 is the EMPIRICALLY VALID cooperative geometry (512x512 failed to
// launch twice). 1024-thread blocks cap VGPR<=128 -> co-residency guaranteed.
//
// R5 core change: cg::grid.sync() costs ~35us fixed (s_sleep-backoff protocol
// in __ockl_grid_sync); replace 179 of 180 with a hand-rolled monotonic
// arrival barrier (tight spin + __threadfence both sides) at ~3-6us.

struct Params {
  const float* action;   // [B][NE]
  const float* pos0;     // [B][NV][3]
  const float* vel0;     // [B][NV][3]
  const float* rest_len; // [NE]
  const float* mass;     // [NV]
  const int* edge_i;     // [NE]
  const int* edge_j;     // [NE]
  float* out;            // [B][NSUB][NV][3]
  float4* pos;           // [NV*32]
  float4* Q0;            // ping-pong: holds r0 (k=0) or Ap_{k-1}
  float4* Q1;
  float* rest_eff;       // [NE][32]
  int* adj_off;          // [2NE] neighbor vertex byte offset (u*512)
  int* adjE_off;         // [2NE] edge byte offset into rest_eff (e*128)
  int* row_ptr;          // [NV+1]
  int* cursor;           // [NV]
  double* Pd;            // [2 parity][96][256] per-block partials
  unsigned* barcnt;      // monotonic barrier counter
};

__device__ __forceinline__ float4 f4(float3 a) { return make_float4(a.x, a.y, a.z, 0.f); }

// Monotonic grid barrier. Each block arrives once (fetch_add), spins until
// count reaches 256*epoch. No reset -> no ABA. threadfence = agent-scope
// release (wb L2) before arrive / acquire (inv L1+L2) after spin, giving
// cross-XCD visibility for the plain loads/stores of qWr/Pd/pos.
// Safe only because cooperative launch guarantees all 256 blocks co-resident.
__device__ __forceinline__ void fast_bar(unsigned* cnt, unsigned target) {
  __syncthreads();  // all waves' stores retired (vmcnt(0) before s_barrier)
  if (threadIdx.x == 0) {
    __threadfence();  // release: flush this XCD's L2 to coherence point
    __hip_atomic_fetch_add(cnt, 1u, __ATOMIC_RELAXED, __HIP_MEMORY_SCOPE_AGENT);
    while (__hip_atomic_load(cnt, __ATOMIC_RELAXED, __HIP_MEMORY_SCOPE_AGENT) < target)
      __builtin_amdgcn_s_sleep(2);
    __threadfence();  // acquire: invalidate stale L1/L2 before reads
  }
  __syncthreads();
}

// End-of-phase publish: block partial of 3 per-batch doubles -> Pd[par][q][blk].
__device__ __forceinline__ void publish_store(double* Pd, int par, double d0, double d1,
                                              double d2, double* lds) {
  d0 += __shfl_down(d0, 32);  // lane L += L+32: same batch, paired vertex
  d1 += __shfl_down(d1, 32);
  d2 += __shfl_down(d2, 32);
  const int lane = threadIdx.x & 63, w = threadIdx.x >> 6;
  if (lane < 32) {
    lds[w * 96 + lane] = d0;
    lds[w * 96 + 32 + lane] = d1;
    lds[w * 96 + 64 + lane] = d2;
  }
  __syncthreads();
  if (threadIdx.x < 96) {
    double s = 0.0;
#pragma unroll
    for (int ww = 0; ww < BLOCK / 64; ++ww) s += lds[ww * 96 + threadIdx.x];
    Pd[(size_t)par * 96 * 256 + (size_t)threadIdx.x * 256 + blockIdx.x] = s;
  }
  __syncthreads();
}

// Start-of-phase reduce: sum Pd[par][q][0..255] -> lds_acc[q] (deterministic).
__device__ __forceinline__ void reduce_in(const double* Pd, int par,
                                          double* lds_part, double* lds_acc) {
  const int tid = threadIdx.x;
  const int q = tid >> 3, c = tid & 7;
  if (q < 96) {
    const double* src = Pd + (size_t)par * 96 * 256 + (size_t)q * 256 + c * 32;
    double s = 0.0;
#pragma unroll
    for (int i = 0; i < 32; ++i) s += src[i];
    lds_part[q * 8 + c] = s;
  }
  __syncthreads();
  if (tid < 96) {
    double s = 0.0;
#pragma unroll
    for (int c2 = 0; c2 < 8; ++c2) s += lds_part[tid * 8 + c2];
    lds_acc[tid] = s;
  }
  __syncthreads();
}

__global__ void __launch_bounds__(BLOCK) mass_spring_kernel(Params P) {
  cg::grid_group grid = cg::this_grid();
  __shared__ double lds_red[(BLOCK / 64) * 96];  // 12 KB
  __shared__ double lds_part[96 * 8];            // 6 KB
  __shared__ double lds_acc[96];                 // 768 B
  __shared__ int lds_scan[BLOCK];                // 4 KB

  const int tid = threadIdx.x;
  const int gtid = blockIdx.x * BLOCK + tid;
  const int b = tid & 31;
  const int v = gtid >> 5;
  const int vb = v * 32 + b;
  const int b16 = b * 16, b4 = b * 4;
  unsigned ep = 0;  // barrier epoch (uniform across all blocks)

  // ---------- setup ----------
  for (int i = gtid; i < NEDGE * 32; i += GRID * BLOCK) {
    const int e = i >> 5, bb = i & 31;
    P.rest_eff[e * 32 + bb] = P.rest_len[e] * (1.0f + P.action[bb * NEDGE + e]);
  }
  float3 pv, vv;
  pv.x = P.pos0[(b * NVERT + v) * 3 + 0];
  pv.y = P.pos0[(b * NVERT + v) * 3 + 1];
  pv.z = P.pos0[(b * NVERT + v) * 3 + 2];
  vv.x = P.vel0[(b * NVERT + v) * 3 + 0];
  vv.y = P.vel0[(b * NVERT + v) * 3 + 1];
  vv.z = P.vel0[(b * NVERT + v) * 3 + 2];
  P.pos[vb] = f4(pv);
  if (gtid < NVERT) P.cursor[gtid] = 0;
  if (gtid == 0) *P.barcnt = 0u;  // ws is poisoned 0xAA each call
  grid.sync();  // the ONE slow sync: publishes barcnt=0 device-wide

  if (gtid < NEDGE) {
    atomicAdd(&P.cursor[P.edge_i[gtid]], 1);
    atomicAdd(&P.cursor[P.edge_j[gtid]], 1);
  }
  fast_bar(P.barcnt, ++ep * GRID);

  if (blockIdx.x == 0) {  // exclusive scan of degrees, 8 per thread
    const int base = tid * (NVERT / BLOCK);
    int loc[NVERT / BLOCK];
    int sum = 0;
#pragma unroll
    for (int i = 0; i < NVERT / BLOCK; ++i) { loc[i] = P.cursor[base + i]; sum += loc[i]; }
    lds_scan[tid] = sum;
    __syncthreads();
    for (int off = 1; off < BLOCK; off <<= 1) {
      int t = 0;
      if (tid >= off) t = lds_scan[tid - off];
      __syncthreads();
      if (tid >= off) lds_scan[tid] += t;
      __syncthreads();
    }
    int run = lds_scan[tid] - sum;
#pragma unroll
    for (int i = 0; i < NVERT / BLOCK; ++i) {
      P.row_ptr[base + i] = run;
      P.cursor[base + i] = run;
      run += loc[i];
    }
    if (tid == BLOCK - 1) P.row_ptr[NVERT] = run;
  }
  fast_bar(P.barcnt, ++ep * GRID);

  if (gtid < NEDGE) {  // adjacency as precomputed byte offsets
    const int ei = P.edge_i[gtid], ej = P.edge_j[gtid];
    const int ai = atomicAdd(&P.cursor[ei], 1);
    P.adj_off[ai] = ej * 512; P.adjE_off[ai] = gtid * 128;
    const int aj = atomicAdd(&P.cursor[ej], 1);
    P.adj_off[aj] = ei * 512; P.adjE_off[aj] = gtid * 128;
  }
  fast_bar(P.barcnt, ++ep * GRID);

  const float m_v = P.mass[v];
  const int rbeg = P.row_ptr[v], rend = P.row_ptr[v + 1];
  const float degf = (float)(rend - rbeg);

  float4* qRd = P.Q0;
  float4* qWr = P.Q1;
  int pub = 0;  // publish counter; parity = pub & 1

  for (int s = 0; s < NSUB; ++s) {
    // ---------- F: spring force; write r0 into qRd for k=0's gather ----------
    float fx = 0.f, fy = 0.f, fz = 0.f;
    for (int a = rbeg; a < rend; ++a) {
      const int off = P.adj_off[a];
      const float4 pu = *(const float4*)((const char*)P.pos + off + b16);
      const float re = *(const float*)((const char*)P.rest_eff + P.adjE_off[a] + b4);
      const float dx = pv.x - pu.x, dy = pv.y - pu.y, dz = pv.z - pu.z;
      const float l = sqrtf(dx * dx + dy * dy + dz * dz);
      const float coef = -KS * (l - re) / fmaxf(l, 1e-6f);
      fx += coef * dx; fy += coef * dy; fz += coef * dz;
    }
    float3 rv;
    rv.x = m_v * vv.x + DT * fx;
    rv.y = m_v * vv.y + DT * (fy - 9.8f * m_v);
    rv.z = m_v * vv.z + DT * fz;
    qRd[vb] = f4(rv);  // r0 staged for k=0 gather
    float3 xacc = make_float3(0.f, 0.f, 0.f);
    float3 pc = rv;                 // p_k (registers)
    float3 ap;                      // Ap_k (registers)
    float3 Sr, Sp;                  // neighbor sums of r_k, p_k (registers)
    fast_bar(P.barcnt, ++ep * GRID);

    // ---------- CG: one barrier per iteration, 1-array gather ----------
    for (int k = 0; k < NCG; ++k) {
      if (k == 0) {
        float sx = 0.f, sy = 0.f, sz = 0.f;  // sum r0[u]
#pragma unroll 4
        for (int a = rbeg; a < rend; ++a) {
          const float4 qu = *(const float4*)((const char*)qRd + P.adj_off[a] + b16);
          sx += qu.x; sy += qu.y; sz += qu.z;
        }
        Sr = make_float3(sx, sy, sz);
        Sp = Sr;  // p0 = r0
        ap.x = (m_v + degf) * pc.x - Sp.x;
        ap.y = (m_v + degf) * pc.y - Sp.y;
        ap.z = (m_v + degf) * pc.z - Sp.z;
      } else {
        // overlap: gather S_q = sum Ap_{k-1}[u] while reducing partials
        float sx = 0.f, sy = 0.f, sz = 0.f;
#pragma unroll 4
        for (int a = rbeg; a < rend; ++a) {
          const float4 qu = *(const float4*)((const char*)qRd + P.adj_off[a] + b16);
          sx += qu.x; sy += qu.y; sz += qu.z;
        }
        reduce_in(P.Pd, (pub + 1) & 1, lds_part, lds_acc);  // (pub-1)&1
        const double rsx = lds_acc[b];        // |r_{k-1}|^2 (exact)
        const double pq  = lds_acc[32 + b];   // p.Ap
        const double qq  = lds_acc[64 + b];   // Ap.Ap
        const float alpha = (float)(rsx / (pq + 1e-12));
        const double rs_rec = (double)alpha * (double)alpha * qq - rsx;
        const float beta = (float)(rs_rec / (rsx + 1e-12));
        xacc.x += alpha * pc.x; xacc.y += alpha * pc.y; xacc.z += alpha * pc.z;
        rv.x -= alpha * ap.x; rv.y -= alpha * ap.y; rv.z -= alpha * ap.z;
        Sr.x -= alpha * sx; Sr.y -= alpha * sy; Sr.z -= alpha * sz;
        pc.x = rv.x + beta * pc.x; pc.y = rv.y + beta * pc.y; pc.z = rv.z + beta * pc.z;
        Sp.x = Sr.x + beta * Sp.x; Sp.y = Sr.y + beta * Sp.y; Sp.z = Sr.z + beta * Sp.z;
        ap.x = (m_v + degf) * pc.x - Sp.x;
        ap.y = (m_v + degf) * pc.y - Sp.y;
        ap.z = (m_v + degf) * pc.z - Sp.z;
      }
      qWr[vb] = f4(ap);
      publish_store(P.Pd, pub & 1,
                    (double)(rv.x * rv.x) + (double)(rv.y * rv.y) + (double)(rv.z * rv.z),
                    (double)(pc.x * ap.x) + (double)(pc.y * ap.y) + (double)(pc.z * ap.z),
                    (double)(ap.x * ap.x) + (double)(ap.y * ap.y) + (double)(ap.z * ap.z),
                    lds_red);
      ++pub;
      float4* t = qRd; qRd = qWr; qWr = t;
      fast_bar(P.barcnt, ++ep * GRID);
    }

    // ---------- W: final alpha, integrate, write out ----------
    {
      reduce_in(P.Pd, (pub + 1) & 1, lds_part, lds_acc);
      const double rsx = lds_acc[b];
      const double pq  = lds_acc[32 + b];
      const float alpha = (float)(rsx / (pq + 1e-12));
      xacc.x += alpha * pc.x; xacc.y += alpha * pc.y; xacc.z += alpha * pc.z;
      vv = xacc;
      pv.x += DT * vv.x; pv.y += DT * vv.y; pv.z += DT * vv.z;
      P.pos[vb] = f4(pv);
      float* o = P.out + ((size_t)(b * NSUB + s) * NVERT + (size_t)v) * 3;
      o[0] = pv.x; o[1] = pv.y; o[2] = pv.z;
      fast_bar(P.barcnt, ++ep * GRID);
    }
  }
}

extern "C" void kernel_launch(void* const* d_in, const int* in_sizes, int n_in,
                              void* d_out, int out_size, void* d_ws, size_t ws_size,
                              hipStream_t stream) {
  Params P;
  P.action = (const float*)d_in[0];
  P.pos0 = (const float*)d_in[1];
  P.vel0 = (const float*)d_in[2];
  P.rest_len = (const float*)d_in[3];
  P.mass = (const float*)d_in[4];
  P.edge_i = (const int*)d_in[5];
  P.edge_j = (const int*)d_in[6];
  P.out = (float*)d_out;

  char* w = (char*)d_ws;
  auto alloc = [&](size_t bytes) {
    char* p = w;
    w += (bytes + 255) & ~(size_t)255;
    return p;
  };
  const size_t vec_bytes = (size_t)NVERT * 32 * sizeof(float4);  // 4 MB
  P.pos = (float4*)alloc(vec_bytes);
  P.Q0  = (float4*)alloc(vec_bytes);
  P.Q1  = (float4*)alloc(vec_bytes);
  P.rest_eff = (float*)alloc((size_t)NEDGE * 32 * sizeof(float));
  P.adj_off  = (int*)alloc((size_t)2 * NEDGE * sizeof(int));
  P.adjE_off = (int*)alloc((size_t)2 * NEDGE * sizeof(int));
  P.row_ptr  = (int*)alloc((size_t)(NVERT + 1) * sizeof(int));
  P.cursor   = (int*)alloc((size_t)NVERT * sizeof(int));
  P.Pd       = (double*)alloc((size_t)2 * 96 * 256 * sizeof(double));
  P.barcnt   = (unsigned*)alloc(256);

  void* args[] = { &P };
  hipLaunchCooperativeKernel(reinterpret_cast<void*>(mass_spring_kernel),
                             dim3(GRID), dim3(BLOCK), args, 0, stream);
}

// Round 7
// 4308.023 us; speedup vs baseline: 3.0181x; 1.5389x over previous
//
#include <hip/hip_runtime.h>
#include <hip/hip_cooperative_groups.h>
#include <math.h>

namespace cg = cooperative_groups;

#define NVERT 8192
#define NEDGE 65536
#define NSUB 8
#define NCG 20
#define GRID 256
#define BLOCK 1024
#define DT 0.01f
#define KS 10000.0f
// 256x1024: the empirically valid cooperative geometry (512x512 never launches).
//
// R6 core change: NO cache-maintenance ops in steady state. R5's ~30us/phase
// fixed cost tracked to the 2x __threadfence (agent release/acquire -> L2
// writeback/invalidate tag-walk, traffic-independent). Replace fences with
// per-access device-coherent exchange: all cross-block payloads (Q, pos, Pd)
// use agent-scope RELAXED 8-byte atomics (-> global_*_dwordx2 sc1, served at
// L3, compiler-pipelined). Read-only data (adjacency, rest_eff) now stays in
// L1/L2 across all 176 phases. fast_bar: waitcnt-drained sc1 stores + relaxed
// fetch_add + relaxed spin -> zero fences.

struct Params {
  const float* action;   // [B][NE]
  const float* pos0;     // [B][NV][3]
  const float* vel0;     // [B][NV][3]
  const float* rest_len; // [NE]
  const float* mass;     // [NV]
  const int* edge_i;     // [NE]
  const int* edge_j;     // [NE]
  float* out;            // [B][NSUB][NV][3]
  float4* pos;           // [NV*32] exchanged (sc1)
  float4* Q0;            // ping-pong Ap / r0 staging (sc1)
  float4* Q1;
  float* rest_eff;       // [NE][32]  read-only after setup (cached)
  int* adj_off;          // [2NE] neighbor vertex byte offset (u*512), cached
  int* adjE_off;         // [2NE] edge byte offset (e*128), cached
  int* row_ptr;          // [NV+1]
  int* cursor;           // [NV]
  double* Pd;            // [2 parity][256 block][96 q] partials (sc1)
  unsigned* barcnt;      // monotonic barrier counter
};

union U64F4 { unsigned long long u[2]; float4 f; };
union U64D  { unsigned long long u;    double d; };

__device__ __forceinline__ float4 ld_dev(const float4* p) {
  U64F4 r;
  r.u[0] = __hip_atomic_load((const unsigned long long*)p,     __ATOMIC_RELAXED, __HIP_MEMORY_SCOPE_AGENT);
  r.u[1] = __hip_atomic_load((const unsigned long long*)p + 1, __ATOMIC_RELAXED, __HIP_MEMORY_SCOPE_AGENT);
  return r.f;
}
__device__ __forceinline__ void st_dev(float4* p, float4 v) {
  U64F4 r; r.f = v;
  __hip_atomic_store((unsigned long long*)p,     r.u[0], __ATOMIC_RELAXED, __HIP_MEMORY_SCOPE_AGENT);
  __hip_atomic_store((unsigned long long*)p + 1, r.u[1], __ATOMIC_RELAXED, __HIP_MEMORY_SCOPE_AGENT);
}
__device__ __forceinline__ double lddbl_dev(const double* p) {
  U64D r;
  r.u = __hip_atomic_load((const unsigned long long*)p, __ATOMIC_RELAXED, __HIP_MEMORY_SCOPE_AGENT);
  return r.d;
}
__device__ __forceinline__ void stdbl_dev(double* p, double v) {
  U64D r; r.d = v;
  __hip_atomic_store((unsigned long long*)p, r.u, __ATOMIC_RELAXED, __HIP_MEMORY_SCOPE_AGENT);
}

__device__ __forceinline__ float4 f4(float3 a) { return make_float4(a.x, a.y, a.z, 0.f); }

// Fence-free monotonic grid barrier. Payload stores are sc1 (at L3 once
// vmcnt-drained by __syncthreads' s_waitcnt before s_barrier); arrival is a
// relaxed agent fetch_add; payload loads are sc1 so no stale cache possible.
__device__ __forceinline__ void fast_bar(unsigned* cnt, unsigned target) {
  __syncthreads();
  if (threadIdx.x == 0) {
    __hip_atomic_fetch_add(cnt, 1u, __ATOMIC_RELAXED, __HIP_MEMORY_SCOPE_AGENT);
    while (__hip_atomic_load(cnt, __ATOMIC_RELAXED, __HIP_MEMORY_SCOPE_AGENT) < target)
      __builtin_amdgcn_s_sleep(1);
  }
  __syncthreads();
}

// End-of-phase publish: block partial of 3 per-batch doubles -> Pd[par][blk][0..95].
__device__ __forceinline__ void publish_store(double* Pd, int par, double d0, double d1,
                                              double d2, double* lds) {
  d0 += __shfl_down(d0, 32);  // lane L += L+32: same batch, paired vertex
  d1 += __shfl_down(d1, 32);
  d2 += __shfl_down(d2, 32);
  const int lane = threadIdx.x & 63, w = threadIdx.x >> 6;
  if (lane < 32) {
    lds[w * 96 + lane] = d0;
    lds[w * 96 + 32 + lane] = d1;
    lds[w * 96 + 64 + lane] = d2;
  }
  __syncthreads();
  if (threadIdx.x < 96) {
    double s = 0.0;
#pragma unroll
    for (int ww = 0; ww < BLOCK / 64; ++ww) s += lds[ww * 96 + threadIdx.x];
    stdbl_dev(&Pd[(size_t)par * 256 * 96 + (size_t)blockIdx.x * 96 + threadIdx.x], s);
  }
  __syncthreads();
}

// Start-of-phase reduce: sum Pd[par][0..255][q] -> lds_acc[q]. Coalesced:
// at fixed j, threads 0..95 (g=0) read 96 consecutive doubles of one block row.
__device__ __forceinline__ void reduce_in(const double* Pd, int par,
                                          double* lds_part, double* lds_acc) {
  const int tid = threadIdx.x;
  if (tid < 768) {
    const int g = tid / 96, q = tid - g * 96;  // g: 8 groups of 32 blocks
    const double* base = Pd + (size_t)par * 256 * 96 + q;
    double s = 0.0;
#pragma unroll
    for (int j = 0; j < 32; ++j) s += lddbl_dev(base + (size_t)(g * 32 + j) * 96);
    lds_part[tid] = s;
  }
  __syncthreads();
  if (tid < 96) {
    double s = 0.0;
#pragma unroll
    for (int g2 = 0; g2 < 8; ++g2) s += lds_part[g2 * 96 + tid];
    lds_acc[tid] = s;
  }
  __syncthreads();
}

__global__ void __launch_bounds__(BLOCK) mass_spring_kernel(Params P) {
  cg::grid_group grid = cg::this_grid();
  __shared__ double lds_red[(BLOCK / 64) * 96];  // 12 KB
  __shared__ double lds_part[768];               // 6 KB
  __shared__ double lds_acc[96];                 // 768 B
  __shared__ int lds_scan[BLOCK];                // 4 KB

  const int tid = threadIdx.x;
  const int gtid = blockIdx.x * BLOCK + tid;
  const int b = tid & 31;
  const int v = gtid >> 5;
  const int vb = v * 32 + b;
  const int b16 = b * 16, b4 = b * 4;
  unsigned ep = 0;

  // ---------- setup (uses real grid.sync: full fences publish plain writes) --
  for (int i = gtid; i < NEDGE * 32; i += GRID * BLOCK) {
    const int e = i >> 5, bb = i & 31;
    P.rest_eff[e * 32 + bb] = P.rest_len[e] * (1.0f + P.action[bb * NEDGE + e]);
  }
  float3 pv, vv;
  pv.x = P.pos0[(b * NVERT + v) * 3 + 0];
  pv.y = P.pos0[(b * NVERT + v) * 3 + 1];
  pv.z = P.pos0[(b * NVERT + v) * 3 + 2];
  vv.x = P.vel0[(b * NVERT + v) * 3 + 0];
  vv.y = P.vel0[(b * NVERT + v) * 3 + 1];
  vv.z = P.vel0[(b * NVERT + v) * 3 + 2];
  st_dev(&P.pos[vb], f4(pv));
  if (gtid < NVERT) P.cursor[gtid] = 0;
  if (gtid == 0) *P.barcnt = 0u;
  grid.sync();

  if (gtid < NEDGE) {
    atomicAdd(&P.cursor[P.edge_i[gtid]], 1);
    atomicAdd(&P.cursor[P.edge_j[gtid]], 1);
  }
  grid.sync();

  if (blockIdx.x == 0) {  // exclusive scan of degrees, 8 per thread
    const int base = tid * (NVERT / BLOCK);
    int loc[NVERT / BLOCK];
    int sum = 0;
#pragma unroll
    for (int i = 0; i < NVERT / BLOCK; ++i) { loc[i] = P.cursor[base + i]; sum += loc[i]; }
    lds_scan[tid] = sum;
    __syncthreads();
    for (int off = 1; off < BLOCK; off <<= 1) {
      int t = 0;
      if (tid >= off) t = lds_scan[tid - off];
      __syncthreads();
      if (tid >= off) lds_scan[tid] += t;
      __syncthreads();
    }
    int run = lds_scan[tid] - sum;
#pragma unroll
    for (int i = 0; i < NVERT / BLOCK; ++i) {
      P.row_ptr[base + i] = run;
      P.cursor[base + i] = run;
      run += loc[i];
    }
    if (tid == BLOCK - 1) P.row_ptr[NVERT] = run;
  }
  grid.sync();

  if (gtid < NEDGE) {  // adjacency as precomputed byte offsets
    const int ei = P.edge_i[gtid], ej = P.edge_j[gtid];
    const int ai = atomicAdd(&P.cursor[ei], 1);
    P.adj_off[ai] = ej * 512; P.adjE_off[ai] = gtid * 128;
    const int aj = atomicAdd(&P.cursor[ej], 1);
    P.adj_off[aj] = ei * 512; P.adjE_off[aj] = gtid * 128;
  }
  grid.sync();  // last full fence: adjacency/rest_eff/row_ptr now L3-published

  const float m_v = P.mass[v];
  const int rbeg = P.row_ptr[v], rend = P.row_ptr[v + 1];
  const float degf = (float)(rend - rbeg);

  float4* qRd = P.Q0;
  float4* qWr = P.Q1;
  int pub = 0;  // publish counter; parity = pub & 1

  for (int s = 0; s < NSUB; ++s) {
    // ---------- F: spring force; stage r0 into qRd ----------
    float fx = 0.f, fy = 0.f, fz = 0.f;
    for (int a = rbeg; a < rend; ++a) {
      const int off = P.adj_off[a];
      const float4 pu = ld_dev((const float4*)((const char*)P.pos + off + b16));
      const float re = *(const float*)((const char*)P.rest_eff + P.adjE_off[a] + b4);
      const float dx = pv.x - pu.x, dy = pv.y - pu.y, dz = pv.z - pu.z;
      const float l = sqrtf(dx * dx + dy * dy + dz * dz);
      const float coef = -KS * (l - re) / fmaxf(l, 1e-6f);
      fx += coef * dx; fy += coef * dy; fz += coef * dz;
    }
    float3 rv;
    rv.x = m_v * vv.x + DT * fx;
    rv.y = m_v * vv.y + DT * (fy - 9.8f * m_v);
    rv.z = m_v * vv.z + DT * fz;
    st_dev(&qRd[vb], f4(rv));  // r0 staged for k=0 gather
    float3 xacc = make_float3(0.f, 0.f, 0.f);
    float3 pc = rv;                 // p_k (registers)
    float3 ap;                      // Ap_k (registers)
    float3 Sr, Sp;                  // neighbor sums of r_k, p_k (registers)
    fast_bar(P.barcnt, ++ep * GRID);

    // ---------- CG: one barrier per iteration, 1-array sc1 gather ----------
    for (int k = 0; k < NCG; ++k) {
      if (k == 0) {
        float sx = 0.f, sy = 0.f, sz = 0.f;  // sum r0[u]
#pragma unroll 4
        for (int a = rbeg; a < rend; ++a) {
          const float4 qu = ld_dev((const float4*)((const char*)qRd + P.adj_off[a] + b16));
          sx += qu.x; sy += qu.y; sz += qu.z;
        }
        Sr = make_float3(sx, sy, sz);
        Sp = Sr;  // p0 = r0
        ap.x = (m_v + degf) * pc.x - Sp.x;
        ap.y = (m_v + degf) * pc.y - Sp.y;
        ap.z = (m_v + degf) * pc.z - Sp.z;
      } else {
        // overlap: gather S_q = sum Ap_{k-1}[u] while reducing partials
        float sx = 0.f, sy = 0.f, sz = 0.f;
#pragma unroll 4
        for (int a = rbeg; a < rend; ++a) {
          const float4 qu = ld_dev((const float4*)((const char*)qRd + P.adj_off[a] + b16));
          sx += qu.x; sy += qu.y; sz += qu.z;
        }
        reduce_in(P.Pd, (pub + 1) & 1, lds_part, lds_acc);  // (pub-1)&1
        const double rsx = lds_acc[b];        // |r_{k-1}|^2 (exact)
        const double pq  = lds_acc[32 + b];   // p.Ap
        const double qq  = lds_acc[64 + b];   // Ap.Ap
        const float alpha = (float)(rsx / (pq + 1e-12));
        const double rs_rec = (double)alpha * (double)alpha * qq - rsx;
        const float beta = (float)(rs_rec / (rsx + 1e-12));
        xacc.x += alpha * pc.x; xacc.y += alpha * pc.y; xacc.z += alpha * pc.z;
        rv.x -= alpha * ap.x; rv.y -= alpha * ap.y; rv.z -= alpha * ap.z;
        Sr.x -= alpha * sx; Sr.y -= alpha * sy; Sr.z -= alpha * sz;
        pc.x = rv.x + beta * pc.x; pc.y = rv.y + beta * pc.y; pc.z = rv.z + beta * pc.z;
        Sp.x = Sr.x + beta * Sp.x; Sp.y = Sr.y + beta * Sp.y; Sp.z = Sr.z + beta * Sp.z;
        ap.x = (m_v + degf) * pc.x - Sp.x;
        ap.y = (m_v + degf) * pc.y - Sp.y;
        ap.z = (m_v + degf) * pc.z - Sp.z;
      }
      st_dev(&qWr[vb], f4(ap));
      publish_store(P.Pd, pub & 1,
                    (double)(rv.x * rv.x) + (double)(rv.y * rv.y) + (double)(rv.z * rv.z),
                    (double)(pc.x * ap.x) + (double)(pc.y * ap.y) + (double)(pc.z * ap.z),
                    (double)(ap.x * ap.x) + (double)(ap.y * ap.y) + (double)(ap.z * ap.z),
                    lds_red);
      ++pub;
      float4* t = qRd; qRd = qWr; qWr = t;
      fast_bar(P.barcnt, ++ep * GRID);
    }

    // ---------- W: final alpha, integrate, write out ----------
    {
      reduce_in(P.Pd, (pub + 1) & 1, lds_part, lds_acc);
      const double rsx = lds_acc[b];
      const double pq  = lds_acc[32 + b];
      const float alpha = (float)(rsx / (pq + 1e-12));
      xacc.x += alpha * pc.x; xacc.y += alpha * pc.y; xacc.z += alpha * pc.z;
      vv = xacc;
      pv.x += DT * vv.x; pv.y += DT * vv.y; pv.z += DT * vv.z;
      st_dev(&P.pos[vb], f4(pv));
      float* o = P.out + ((size_t)(b * NSUB + s) * NVERT + (size_t)v) * 3;
      o[0] = pv.x; o[1] = pv.y; o[2] = pv.z;  // plain: flushed at kernel end
      fast_bar(P.barcnt, ++ep * GRID);
    }
  }
}

extern "C" void kernel_launch(void* const* d_in, const int* in_sizes, int n_in,
                              void* d_out, int out_size, void* d_ws, size_t ws_size,
                              hipStream_t stream) {
  Params P;
  P.action = (const float*)d_in[0];
  P.pos0 = (const float*)d_in[1];
  P.vel0 = (const float*)d_in[2];
  P.rest_len = (const float*)d_in[3];
  P.mass = (const float*)d_in[4];
  P.edge_i = (const int*)d_in[5];
  P.edge_j = (const int*)d_in[6];
  P.out = (float*)d_out;

  char* w = (char*)d_ws;
  auto alloc = [&](size_t bytes) {
    char* p = w;
    w += (bytes + 255) & ~(size_t)255;
    return p;
  };
  const size_t vec_bytes = (size_t)NVERT * 32 * sizeof(float4);  // 4 MB
  P.pos = (float4*)alloc(vec_bytes);
  P.Q0  = (float4*)alloc(vec_bytes);
  P.Q1  = (float4*)alloc(vec_bytes);
  P.rest_eff = (float*)alloc((size_t)NEDGE * 32 * sizeof(float));
  P.adj_off  = (int*)alloc((size_t)2 * NEDGE * sizeof(int));
  P.adjE_off = (int*)alloc((size_t)2 * NEDGE * sizeof(int));
  P.row_ptr  = (int*)alloc((size_t)(NVERT + 1) * sizeof(int));
  P.cursor   = (int*)alloc((size_t)NVERT * sizeof(int));
  P.Pd       = (double*)alloc((size_t)2 * 256 * 96 * sizeof(double));
  P.barcnt   = (unsigned*)alloc(256);

  void* args[] = { &P };
  hipLaunchCooperativeKernel(reinterpret_cast<void*>(mass_spring_kernel),
                             dim3(GRID), dim3(BLOCK), args, 0, stream);
}

// Round 8
// 3241.880 us; speedup vs baseline: 4.0106x; 1.3289x over previous
//
#include <hip/hip_runtime.h>
#include <hip/hip_cooperative_groups.h>
#include <math.h>

namespace cg = cooperative_groups;

#define NVERT 8192
#define NEDGE 65536
#define NSUB 8
#define NCG 20
#define GRID 256
#define BLOCK 1024
#define DT 0.01f
#define KS 10000.0f
#define NGRP 16   // barrier groups
#define GSIZE 16  // blocks per group (NGRP*GSIZE == GRID)
// 256x1024: the empirically valid cooperative geometry (512x512 never launches).
//
// R7 core change: hierarchical fence-free barrier. R6's flat barrier put 256
// fetch_adds AND 256 spin-loads on ONE line -> RMWs queue behind polls at the
// L3 bank (~10us/phase serialization). Now: per-group arrival counters
// (16-way RMW, own lines, never polled), root counter (16 leaders), and
// per-group release flag lines (<=16 pollers each). Critical path after last
// arrival ~3 L3 round trips.

struct Params {
  const float* action;   // [B][NE]
  const float* pos0;     // [B][NV][3]
  const float* vel0;     // [B][NV][3]
  const float* rest_len; // [NE]
  const float* mass;     // [NV]
  const int* edge_i;     // [NE]
  const int* edge_j;     // [NE]
  float* out;            // [B][NSUB][NV][3]
  float4* pos;           // [NV*32] exchanged (sc1)
  float4* Q0;            // ping-pong Ap / r0 staging (sc1)
  float4* Q1;
  float* rest_eff;       // [NE][32]  read-only after setup (cached)
  int* adj_off;          // [2NE] neighbor vertex byte offset (u*512), cached
  int* adjE_off;         // [2NE] edge byte offset (e*128), cached
  int* row_ptr;          // [NV+1]
  int* cursor;           // [NV]
  double* Pd;            // [2 parity][256 block][96 q] partials (sc1)
  unsigned* bar;         // [(NGRP+1+NGRP)*32] uints: grp cnts | root | releases
};

union U64F4 { unsigned long long u[2]; float4 f; };
union U64D  { unsigned long long u;    double d; };

__device__ __forceinline__ float4 ld_dev(const float4* p) {
  U64F4 r;
  r.u[0] = __hip_atomic_load((const unsigned long long*)p,     __ATOMIC_RELAXED, __HIP_MEMORY_SCOPE_AGENT);
  r.u[1] = __hip_atomic_load((const unsigned long long*)p + 1, __ATOMIC_RELAXED, __HIP_MEMORY_SCOPE_AGENT);
  return r.f;
}
__device__ __forceinline__ void st_dev(float4* p, float4 v) {
  U64F4 r; r.f = v;
  __hip_atomic_store((unsigned long long*)p,     r.u[0], __ATOMIC_RELAXED, __HIP_MEMORY_SCOPE_AGENT);
  __hip_atomic_store((unsigned long long*)p + 1, r.u[1], __ATOMIC_RELAXED, __HIP_MEMORY_SCOPE_AGENT);
}
__device__ __forceinline__ double lddbl_dev(const double* p) {
  U64D r;
  r.u = __hip_atomic_load((const unsigned long long*)p, __ATOMIC_RELAXED, __HIP_MEMORY_SCOPE_AGENT);
  return r.d;
}
__device__ __forceinline__ void stdbl_dev(double* p, double v) {
  U64D r; r.d = v;
  __hip_atomic_store((unsigned long long*)p, r.u, __ATOMIC_RELAXED, __HIP_MEMORY_SCOPE_AGENT);
}

__device__ __forceinline__ float4 f4(float3 a) { return make_float4(a.x, a.y, a.z, 0.f); }

// Hierarchical fence-free monotonic grid barrier.
// bar layout (stride 32 uints = 128 B/line): grp g counter @ bar[g*32];
// root @ bar[NGRP*32]; release flag for g @ bar[(NGRP+1+g)*32].
// Payload sc1 stores are drained by the s_waitcnt vmcnt(0) the compiler emits
// before s_barrier (__syncthreads), so arrival implies payload-at-L3.
__device__ __forceinline__ void fast_bar(unsigned* bar, unsigned ep) {
  __syncthreads();
  if (threadIdx.x == 0) {
    const unsigned g = blockIdx.x >> 4;  // blockIdx / GSIZE
    unsigned* rel = bar + (NGRP + 1 + g) * 32;
    const unsigned old = __hip_atomic_fetch_add(bar + g * 32, 1u,
                          __ATOMIC_RELAXED, __HIP_MEMORY_SCOPE_AGENT);
    if (old == GSIZE * ep - 1) {  // last arriver of this group this epoch
      const unsigned old2 = __hip_atomic_fetch_add(bar + NGRP * 32, 1u,
                             __ATOMIC_RELAXED, __HIP_MEMORY_SCOPE_AGENT);
      if (old2 == NGRP * ep - 1) {  // last group: broadcast release
#pragma unroll
        for (int i = 0; i < NGRP; ++i)
          __hip_atomic_store(bar + (NGRP + 1 + i) * 32, ep,
                             __ATOMIC_RELAXED, __HIP_MEMORY_SCOPE_AGENT);
      }
    }
    while (__hip_atomic_load(rel, __ATOMIC_RELAXED, __HIP_MEMORY_SCOPE_AGENT) < ep)
      __builtin_amdgcn_s_sleep(1);
  }
  __syncthreads();
}

// Publish block partial of 3 per-batch doubles -> Pd[par][blk][0..95].
// NOTE: no trailing __syncthreads — MUST be followed by fast_bar (its leading
// sync covers the Pd stores).
__device__ __forceinline__ void publish_store(double* Pd, int par, double d0, double d1,
                                              double d2, double* lds) {
  d0 += __shfl_down(d0, 32);  // lane L += L+32: same batch, paired vertex
  d1 += __shfl_down(d1, 32);
  d2 += __shfl_down(d2, 32);
  const int lane = threadIdx.x & 63, w = threadIdx.x >> 6;
  if (lane < 32) {
    lds[w * 96 + lane] = d0;
    lds[w * 96 + 32 + lane] = d1;
    lds[w * 96 + 64 + lane] = d2;
  }
  __syncthreads();
  if (threadIdx.x < 96) {
    double s = 0.0;
#pragma unroll
    for (int ww = 0; ww < BLOCK / 64; ++ww) s += lds[ww * 96 + threadIdx.x];
    stdbl_dev(&Pd[(size_t)par * 256 * 96 + (size_t)blockIdx.x * 96 + threadIdx.x], s);
  }
}

// Start-of-phase reduce: sum Pd[par][0..255][q] -> lds_acc[q].
__device__ __forceinline__ void reduce_in(const double* Pd, int par,
                                          double* lds_part, double* lds_acc) {
  const int tid = threadIdx.x;
  if (tid < 768) {
    const int g = tid / 96, q = tid - g * 96;  // g: 8 groups of 32 blocks
    const double* base = Pd + (size_t)par * 256 * 96 + q;
    double s = 0.0;
#pragma unroll
    for (int j = 0; j < 32; ++j) s += lddbl_dev(base + (size_t)(g * 32 + j) * 96);
    lds_part[tid] = s;
  }
  __syncthreads();
  if (tid < 96) {
    double s = 0.0;
#pragma unroll
    for (int g2 = 0; g2 < 8; ++g2) s += lds_part[g2 * 96 + tid];
    lds_acc[tid] = s;
  }
  __syncthreads();
}

__global__ void __launch_bounds__(BLOCK) mass_spring_kernel(Params P) {
  cg::grid_group grid = cg::this_grid();
  __shared__ double lds_red[(BLOCK / 64) * 96];  // 12 KB
  __shared__ double lds_part[768];               // 6 KB
  __shared__ double lds_acc[96];                 // 768 B
  __shared__ int lds_scan[BLOCK];                // 4 KB

  const int tid = threadIdx.x;
  const int gtid = blockIdx.x * BLOCK + tid;
  const int b = tid & 31;
  const int v = gtid >> 5;
  const int vb = v * 32 + b;
  const int b16 = b * 16, b4 = b * 4;
  unsigned ep = 0;

  // ---------- setup (real grid.syncs publish plain writes) ----------
  for (int i = gtid; i < NEDGE * 32; i += GRID * BLOCK) {
    const int e = i >> 5, bb = i & 31;
    P.rest_eff[e * 32 + bb] = P.rest_len[e] * (1.0f + P.action[bb * NEDGE + e]);
  }
  float3 pv, vv;
  pv.x = P.pos0[(b * NVERT + v) * 3 + 0];
  pv.y = P.pos0[(b * NVERT + v) * 3 + 1];
  pv.z = P.pos0[(b * NVERT + v) * 3 + 2];
  vv.x = P.vel0[(b * NVERT + v) * 3 + 0];
  vv.y = P.vel0[(b * NVERT + v) * 3 + 1];
  vv.z = P.vel0[(b * NVERT + v) * 3 + 2];
  st_dev(&P.pos[vb], f4(pv));
  if (gtid < NVERT) P.cursor[gtid] = 0;
  if (gtid < (2 * NGRP + 1) * 32) P.bar[gtid] = 0u;
  grid.sync();

  if (gtid < NEDGE) {
    atomicAdd(&P.cursor[P.edge_i[gtid]], 1);
    atomicAdd(&P.cursor[P.edge_j[gtid]], 1);
  }
  grid.sync();

  if (blockIdx.x == 0) {  // exclusive scan of degrees, 8 per thread
    const int base = tid * (NVERT / BLOCK);
    int loc[NVERT / BLOCK];
    int sum = 0;
#pragma unroll
    for (int i = 0; i < NVERT / BLOCK; ++i) { loc[i] = P.cursor[base + i]; sum += loc[i]; }
    lds_scan[tid] = sum;
    __syncthreads();
    for (int off = 1; off < BLOCK; off <<= 1) {
      int t = 0;
      if (tid >= off) t = lds_scan[tid - off];
      __syncthreads();
      if (tid >= off) lds_scan[tid] += t;
      __syncthreads();
    }
    int run = lds_scan[tid] - sum;
#pragma unroll
    for (int i = 0; i < NVERT / BLOCK; ++i) {
      P.row_ptr[base + i] = run;
      P.cursor[base + i] = run;
      run += loc[i];
    }
    if (tid == BLOCK - 1) P.row_ptr[NVERT] = run;
  }
  grid.sync();

  if (gtid < NEDGE) {  // adjacency as precomputed byte offsets
    const int ei = P.edge_i[gtid], ej = P.edge_j[gtid];
    const int ai = atomicAdd(&P.cursor[ei], 1);
    P.adj_off[ai] = ej * 512; P.adjE_off[ai] = gtid * 128;
    const int aj = atomicAdd(&P.cursor[ej], 1);
    P.adj_off[aj] = ei * 512; P.adjE_off[aj] = gtid * 128;
  }
  grid.sync();  // adjacency/rest_eff/row_ptr now published everywhere

  const float m_v = P.mass[v];
  const int rbeg = P.row_ptr[v], rend = P.row_ptr[v + 1];
  const float degf = (float)(rend - rbeg);

  float4* qRd = P.Q0;
  float4* qWr = P.Q1;
  int pub = 0;  // publish counter; parity = pub & 1

  for (int s = 0; s < NSUB; ++s) {
    // ---------- F: spring force; stage r0 into qRd ----------
    float fx = 0.f, fy = 0.f, fz = 0.f;
    for (int a = rbeg; a < rend; ++a) {
      const int off = P.adj_off[a];
      const float4 pu = ld_dev((const float4*)((const char*)P.pos + off + b16));
      const float re = *(const float*)((const char*)P.rest_eff + P.adjE_off[a] + b4);
      const float dx = pv.x - pu.x, dy = pv.y - pu.y, dz = pv.z - pu.z;
      const float l = sqrtf(dx * dx + dy * dy + dz * dz);
      const float coef = -KS * (l - re) / fmaxf(l, 1e-6f);
      fx += coef * dx; fy += coef * dy; fz += coef * dz;
    }
    float3 rv;
    rv.x = m_v * vv.x + DT * fx;
    rv.y = m_v * vv.y + DT * (fy - 9.8f * m_v);
    rv.z = m_v * vv.z + DT * fz;
    st_dev(&qRd[vb], f4(rv));  // r0 staged for k=0 gather
    float3 xacc = make_float3(0.f, 0.f, 0.f);
    float3 pc = rv;                 // p_k (registers)
    float3 ap;                      // Ap_k (registers)
    float3 Sr, Sp;                  // neighbor sums of r_k, p_k (registers)
    fast_bar(P.bar, ++ep);

    // ---------- CG: one barrier per iteration, 1-array sc1 gather ----------
    for (int k = 0; k < NCG; ++k) {
      if (k == 0) {
        float sx = 0.f, sy = 0.f, sz = 0.f;  // sum r0[u]
#pragma unroll 4
        for (int a = rbeg; a < rend; ++a) {
          const float4 qu = ld_dev((const float4*)((const char*)qRd + P.adj_off[a] + b16));
          sx += qu.x; sy += qu.y; sz += qu.z;
        }
        Sr = make_float3(sx, sy, sz);
        Sp = Sr;  // p0 = r0
        ap.x = (m_v + degf) * pc.x - Sp.x;
        ap.y = (m_v + degf) * pc.y - Sp.y;
        ap.z = (m_v + degf) * pc.z - Sp.z;
      } else {
        // gather S_q = sum Ap_{k-1}[u]; then reduce partials
        float sx = 0.f, sy = 0.f, sz = 0.f;
#pragma unroll 4
        for (int a = rbeg; a < rend; ++a) {
          const float4 qu = ld_dev((const float4*)((const char*)qRd + P.adj_off[a] + b16));
          sx += qu.x; sy += qu.y; sz += qu.z;
        }
        reduce_in(P.Pd, (pub + 1) & 1, lds_part, lds_acc);  // (pub-1)&1
        const double rsx = lds_acc[b];        // |r_{k-1}|^2 (exact)
        const double pq  = lds_acc[32 + b];   // p.Ap
        const double qq  = lds_acc[64 + b];   // Ap.Ap
        const float alpha = (float)(rsx / (pq + 1e-12));
        const double rs_rec = (double)alpha * (double)alpha * qq - rsx;
        const float beta = (float)(rs_rec / (rsx + 1e-12));
        xacc.x += alpha * pc.x; xacc.y += alpha * pc.y; xacc.z += alpha * pc.z;
        rv.x -= alpha * ap.x; rv.y -= alpha * ap.y; rv.z -= alpha * ap.z;
        Sr.x -= alpha * sx; Sr.y -= alpha * sy; Sr.z -= alpha * sz;
        pc.x = rv.x + beta * pc.x; pc.y = rv.y + beta * pc.y; pc.z = rv.z + beta * pc.z;
        Sp.x = Sr.x + beta * Sp.x; Sp.y = Sr.y + beta * Sp.y; Sp.z = Sr.z + beta * Sp.z;
        ap.x = (m_v + degf) * pc.x - Sp.x;
        ap.y = (m_v + degf) * pc.y - Sp.y;
        ap.z = (m_v + degf) * pc.z - Sp.z;
      }
      st_dev(&qWr[vb], f4(ap));
      publish_store(P.Pd, pub & 1,
                    (double)(rv.x * rv.x) + (double)(rv.y * rv.y) + (double)(rv.z * rv.z),
                    (double)(pc.x * ap.x) + (double)(pc.y * ap.y) + (double)(pc.z * ap.z),
                    (double)(ap.x * ap.x) + (double)(ap.y * ap.y) + (double)(ap.z * ap.z),
                    lds_red);
      ++pub;
      float4* t = qRd; qRd = qWr; qWr = t;
      fast_bar(P.bar, ++ep);
    }

    // ---------- W: final alpha, integrate, write out ----------
    {
      reduce_in(P.Pd, (pub + 1) & 1, lds_part, lds_acc);
      const double rsx = lds_acc[b];
      const double pq  = lds_acc[32 + b];
      const float alpha = (float)(rsx / (pq + 1e-12));
      xacc.x += alpha * pc.x; xacc.y += alpha * pc.y; xacc.z += alpha * pc.z;
      vv = xacc;
      pv.x += DT * vv.x; pv.y += DT * vv.y; pv.z += DT * vv.z;
      st_dev(&P.pos[vb], f4(pv));
      float* o = P.out + ((size_t)(b * NSUB + s) * NVERT + (size_t)v) * 3;
      o[0] = pv.x; o[1] = pv.y; o[2] = pv.z;  // plain: flushed at kernel end
      fast_bar(P.bar, ++ep);
    }
  }
}

extern "C" void kernel_launch(void* const* d_in, const int* in_sizes, int n_in,
                              void* d_out, int out_size, void* d_ws, size_t ws_size,
                              hipStream_t stream) {
  Params P;
  P.action = (const float*)d_in[0];
  P.pos0 = (const float*)d_in[1];
  P.vel0 = (const float*)d_in[2];
  P.rest_len = (const float*)d_in[3];
  P.mass = (const float*)d_in[4];
  P.edge_i = (const int*)d_in[5];
  P.edge_j = (const int*)d_in[6];
  P.out = (float*)d_out;

  char* w = (char*)d_ws;
  auto alloc = [&](size_t bytes) {
    char* p = w;
    w += (bytes + 255) & ~(size_t)255;
    return p;
  };
  const size_t vec_bytes = (size_t)NVERT * 32 * sizeof(float4);  // 4 MB
  P.pos = (float4*)alloc(vec_bytes);
  P.Q0  = (float4*)alloc(vec_bytes);
  P.Q1  = (float4*)alloc(vec_bytes);
  P.rest_eff = (float*)alloc((size_t)NEDGE * 32 * sizeof(float));
  P.adj_off  = (int*)alloc((size_t)2 * NEDGE * sizeof(int));
  P.adjE_off = (int*)alloc((size_t)2 * NEDGE * sizeof(int));
  P.row_ptr  = (int*)alloc((size_t)(NVERT + 1) * sizeof(int));
  P.cursor   = (int*)alloc((size_t)NVERT * sizeof(int));
  P.Pd       = (double*)alloc((size_t)2 * 256 * 96 * sizeof(double));
  P.bar      = (unsigned*)alloc((size_t)(2 * NGRP + 1) * 32 * sizeof(unsigned));

  void* args[] = { &P };
  hipLaunchCooperativeKernel(reinterpret_cast<void*>(mass_spring_kernel),
                             dim3(GRID), dim3(BLOCK), args, 0, stream);
}

// Round 9
// 2405.202 us; speedup vs baseline: 5.4057x; 1.3479x over previous
//
#include <hip/hip_runtime.h>
#include <hip/hip_cooperative_groups.h>
#include <math.h>

namespace cg = cooperative_groups;

#define NVERT 8192
#define NEDGE 65536
#define NSUB 8
#define NCG 20
#define GRID 256
#define BLOCK 1024
#define DT 0.01f
#define KS 10000.0f
#define NGRP 16   // barrier groups
#define GSIZE 16  // blocks per group (NGRP*GSIZE == GRID)
// 256x1024: the empirically valid cooperative geometry (512x512 never launches).
//
// R8 core change: reduction folded into the barrier hierarchy. R7 had every
// block re-read the full 196 KB Pd slab (50 MB/phase broadcast). Now the
// group's LAST ARRIVER (detected by its arrival fetch_add) reduces its 16
// block-slabs into Gd[par][group][96] inside the barrier's idle shadow
// (overlapped with other groups' arrivals); consumers read only 16x96 f64 =
// 12 KB/block (3 MB/phase). All-f64 fixed-order -> deterministic.

struct Params {
  const float* action;   // [B][NE]
  const float* pos0;     // [B][NV][3]
  const float* vel0;     // [B][NV][3]
  const float* rest_len; // [NE]
  const float* mass;     // [NV]
  const int* edge_i;     // [NE]
  const int* edge_j;     // [NE]
  float* out;            // [B][NSUB][NV][3]
  float4* pos;           // [NV*32] exchanged (sc1)
  float4* Q0;            // ping-pong Ap / r0 staging (sc1)
  float4* Q1;
  float* rest_eff;       // [NE][32]  read-only after setup (cached)
  int* adj_off;          // [2NE] neighbor vertex byte offset (u*512), cached
  int* adjE_off;         // [2NE] edge byte offset (e*128), cached
  int* row_ptr;          // [NV+1]
  int* cursor;           // [NV]
  double* Pd;            // [2 parity][256 block][96 q] per-block partials (sc1)
  double* Gd;            // [2 parity][NGRP group][96 q] group partials (sc1)
  unsigned* bar;         // [(2*NGRP+1)*32] uints: grp cnts | root | releases
};

union U64F4 { unsigned long long u[2]; float4 f; };
union U64D  { unsigned long long u;    double d; };

__device__ __forceinline__ float4 ld_dev(const float4* p) {
  U64F4 r;
  r.u[0] = __hip_atomic_load((const unsigned long long*)p,     __ATOMIC_RELAXED, __HIP_MEMORY_SCOPE_AGENT);
  r.u[1] = __hip_atomic_load((const unsigned long long*)p + 1, __ATOMIC_RELAXED, __HIP_MEMORY_SCOPE_AGENT);
  return r.f;
}
__device__ __forceinline__ void st_dev(float4* p, float4 v) {
  U64F4 r; r.f = v;
  __hip_atomic_store((unsigned long long*)p,     r.u[0], __ATOMIC_RELAXED, __HIP_MEMORY_SCOPE_AGENT);
  __hip_atomic_store((unsigned long long*)p + 1, r.u[1], __ATOMIC_RELAXED, __HIP_MEMORY_SCOPE_AGENT);
}
__device__ __forceinline__ double lddbl_dev(const double* p) {
  U64D r;
  r.u = __hip_atomic_load((const unsigned long long*)p, __ATOMIC_RELAXED, __HIP_MEMORY_SCOPE_AGENT);
  return r.d;
}
__device__ __forceinline__ void stdbl_dev(double* p, double v) {
  U64D r; r.d = v;
  __hip_atomic_store((unsigned long long*)p, r.u, __ATOMIC_RELAXED, __HIP_MEMORY_SCOPE_AGENT);
}

__device__ __forceinline__ float4 f4(float3 a) { return make_float4(a.x, a.y, a.z, 0.f); }

// Plain hierarchical fence-free barrier (for F/W phases: no dots published).
__device__ __forceinline__ void fast_bar(unsigned* bar, unsigned ep) {
  __syncthreads();
  if (threadIdx.x == 0) {
    const unsigned g = blockIdx.x >> 4;
    const unsigned old = __hip_atomic_fetch_add(bar + g * 32, 1u,
                          __ATOMIC_RELAXED, __HIP_MEMORY_SCOPE_AGENT);
    if (old == GSIZE * ep - 1) {
      const unsigned old2 = __hip_atomic_fetch_add(bar + NGRP * 32, 1u,
                             __ATOMIC_RELAXED, __HIP_MEMORY_SCOPE_AGENT);
      if (old2 == NGRP * ep - 1) {
#pragma unroll
        for (int i = 0; i < NGRP; ++i)
          __hip_atomic_store(bar + (NGRP + 1 + i) * 32, ep,
                             __ATOMIC_RELAXED, __HIP_MEMORY_SCOPE_AGENT);
      }
    }
    while (__hip_atomic_load(bar + (NGRP + 1 + (blockIdx.x >> 4)) * 32,
                             __ATOMIC_RELAXED, __HIP_MEMORY_SCOPE_AGENT) < ep)
      __builtin_amdgcn_s_sleep(1);
  }
  __syncthreads();
}

// Barrier WITH in-shadow group reduction. Group-last arriver's threads 0-95
// sum the group's 16 Pd slabs -> Gd[par][g][96] BEFORE arriving at root;
// root release therefore implies all Gd slabs are at L3.
// Pd-visibility: each member's sc1 Pd stores are vmcnt-drained by the leading
// __syncthreads before its arrival RMW (R6/R7-validated ordering).
__device__ __forceinline__ void fast_bar_red(unsigned* bar, unsigned ep,
                                             const double* Pd, double* Gd, int par,
                                             int* lflag) {
  __syncthreads();  // drains this block's Pd sc1 stores; joins all waves
  const unsigned g = blockIdx.x >> 4;
  if (threadIdx.x == 0) {
    const unsigned old = __hip_atomic_fetch_add(bar + g * 32, 1u,
                          __ATOMIC_RELAXED, __HIP_MEMORY_SCOPE_AGENT);
    *lflag = (old == GSIZE * ep - 1);
  }
  __syncthreads();
  if (*lflag) {  // uniform within block
    if (threadIdx.x < 96) {
      const double* base = Pd + (size_t)par * 256 * 96 + (size_t)(g * GSIZE) * 96
                           + threadIdx.x;
      double s = 0.0;
#pragma unroll
      for (int j = 0; j < GSIZE; ++j) s += lddbl_dev(base + j * 96);
      stdbl_dev(&Gd[(size_t)par * NGRP * 96 + g * 96 + threadIdx.x], s);
    }
    __syncthreads();  // drain Gd stores (vmcnt0) before root arrival
    if (threadIdx.x == 0) {
      const unsigned old2 = __hip_atomic_fetch_add(bar + NGRP * 32, 1u,
                             __ATOMIC_RELAXED, __HIP_MEMORY_SCOPE_AGENT);
      if (old2 == NGRP * ep - 1) {
#pragma unroll
        for (int i = 0; i < NGRP; ++i)
          __hip_atomic_store(bar + (NGRP + 1 + i) * 32, ep,
                             __ATOMIC_RELAXED, __HIP_MEMORY_SCOPE_AGENT);
      }
    }
  }
  if (threadIdx.x == 0) {
    while (__hip_atomic_load(bar + (NGRP + 1 + g) * 32,
                             __ATOMIC_RELAXED, __HIP_MEMORY_SCOPE_AGENT) < ep)
      __builtin_amdgcn_s_sleep(1);
  }
  __syncthreads();
}

// Publish block partial of 3 per-batch doubles -> Pd[par][blk][0..95].
// No trailing __syncthreads — MUST be followed by fast_bar_red.
__device__ __forceinline__ void publish_store(double* Pd, int par, double d0, double d1,
                                              double d2, double* lds) {
  d0 += __shfl_down(d0, 32);  // lane L += L+32: same batch, paired vertex
  d1 += __shfl_down(d1, 32);
  d2 += __shfl_down(d2, 32);
  const int lane = threadIdx.x & 63, w = threadIdx.x >> 6;
  if (lane < 32) {
    lds[w * 96 + lane] = d0;
    lds[w * 96 + 32 + lane] = d1;
    lds[w * 96 + 64 + lane] = d2;
  }
  __syncthreads();
  if (threadIdx.x < 96) {
    double s = 0.0;
#pragma unroll
    for (int ww = 0; ww < BLOCK / 64; ++ww) s += lds[ww * 96 + threadIdx.x];
    stdbl_dev(&Pd[(size_t)par * 256 * 96 + (size_t)blockIdx.x * 96 + threadIdx.x], s);
  }
}

// Consumer: read Gd[par][0..15][96] (12 KB) -> lds_acc[q]. Deterministic.
__device__ __forceinline__ void reduce_small(const double* Gd, int par,
                                             double* lds_part, double* lds_acc) {
  const int tid = threadIdx.x;
  if (tid < NGRP * 96)
    lds_part[tid] = lddbl_dev(Gd + (size_t)par * NGRP * 96 + tid);
  __syncthreads();
  if (tid < 96) {
    double s = 0.0;
#pragma unroll
    for (int g = 0; g < NGRP; ++g) s += lds_part[g * 96 + tid];
    lds_acc[tid] = s;
  }
  __syncthreads();
}

__global__ void __launch_bounds__(BLOCK) mass_spring_kernel(Params P) {
  cg::grid_group grid = cg::this_grid();
  __shared__ double lds_red[(BLOCK / 64) * 96];  // 12 KB
  __shared__ double lds_part[NGRP * 96];         // 12 KB
  __shared__ double lds_acc[96];                 // 768 B
  __shared__ int lds_scan[BLOCK];                // 4 KB
  __shared__ int lds_flag;

  const int tid = threadIdx.x;
  const int gtid = blockIdx.x * BLOCK + tid;
  const int b = tid & 31;
  const int v = gtid >> 5;
  const int vb = v * 32 + b;
  const int b16 = b * 16, b4 = b * 4;
  unsigned ep = 0;

  // ---------- setup (real grid.syncs publish plain writes) ----------
  for (int i = gtid; i < NEDGE * 32; i += GRID * BLOCK) {
    const int e = i >> 5, bb = i & 31;
    P.rest_eff[e * 32 + bb] = P.rest_len[e] * (1.0f + P.action[bb * NEDGE + e]);
  }
  float3 pv, vv;
  pv.x = P.pos0[(b * NVERT + v) * 3 + 0];
  pv.y = P.pos0[(b * NVERT + v) * 3 + 1];
  pv.z = P.pos0[(b * NVERT + v) * 3 + 2];
  vv.x = P.vel0[(b * NVERT + v) * 3 + 0];
  vv.y = P.vel0[(b * NVERT + v) * 3 + 1];
  vv.z = P.vel0[(b * NVERT + v) * 3 + 2];
  st_dev(&P.pos[vb], f4(pv));
  if (gtid < NVERT) P.cursor[gtid] = 0;
  if (gtid < (2 * NGRP + 1) * 32) P.bar[gtid] = 0u;
  grid.sync();

  if (gtid < NEDGE) {
    atomicAdd(&P.cursor[P.edge_i[gtid]], 1);
    atomicAdd(&P.cursor[P.edge_j[gtid]], 1);
  }
  grid.sync();

  if (blockIdx.x == 0) {  // exclusive scan of degrees, 8 per thread
    const int base = tid * (NVERT / BLOCK);
    int loc[NVERT / BLOCK];
    int sum = 0;
#pragma unroll
    for (int i = 0; i < NVERT / BLOCK; ++i) { loc[i] = P.cursor[base + i]; sum += loc[i]; }
    lds_scan[tid] = sum;
    __syncthreads();
    for (int off = 1; off < BLOCK; off <<= 1) {
      int t = 0;
      if (tid >= off) t = lds_scan[tid - off];
      __syncthreads();
      if (tid >= off) lds_scan[tid] += t;
      __syncthreads();
    }
    int run = lds_scan[tid] - sum;
#pragma unroll
    for (int i = 0; i < NVERT / BLOCK; ++i) {
      P.row_ptr[base + i] = run;
      P.cursor[base + i] = run;
      run += loc[i];
    }
    if (tid == BLOCK - 1) P.row_ptr[NVERT] = run;
  }
  grid.sync();

  if (gtid < NEDGE) {  // adjacency as precomputed byte offsets
    const int ei = P.edge_i[gtid], ej = P.edge_j[gtid];
    const int ai = atomicAdd(&P.cursor[ei], 1);
    P.adj_off[ai] = ej * 512; P.adjE_off[ai] = gtid * 128;
    const int aj = atomicAdd(&P.cursor[ej], 1);
    P.adj_off[aj] = ei * 512; P.adjE_off[aj] = gtid * 128;
  }
  grid.sync();  // adjacency/rest_eff/row_ptr now published everywhere

  const float m_v = P.mass[v];
  const int rbeg = P.row_ptr[v], rend = P.row_ptr[v + 1];
  const float degf = (float)(rend - rbeg);

  float4* qRd = P.Q0;
  float4* qWr = P.Q1;
  int pub = 0;  // publish counter; parity = pub & 1

  for (int s = 0; s < NSUB; ++s) {
    // ---------- F: spring force; stage r0 into qRd ----------
    float fx = 0.f, fy = 0.f, fz = 0.f;
    for (int a = rbeg; a < rend; ++a) {
      const int off = P.adj_off[a];
      const float4 pu = ld_dev((const float4*)((const char*)P.pos + off + b16));
      const float re = *(const float*)((const char*)P.rest_eff + P.adjE_off[a] + b4);
      const float dx = pv.x - pu.x, dy = pv.y - pu.y, dz = pv.z - pu.z;
      const float l = sqrtf(dx * dx + dy * dy + dz * dz);
      const float coef = -KS * (l - re) / fmaxf(l, 1e-6f);
      fx += coef * dx; fy += coef * dy; fz += coef * dz;
    }
    float3 rv;
    rv.x = m_v * vv.x + DT * fx;
    rv.y = m_v * vv.y + DT * (fy - 9.8f * m_v);
    rv.z = m_v * vv.z + DT * fz;
    st_dev(&qRd[vb], f4(rv));  // r0 staged for k=0 gather
    float3 xacc = make_float3(0.f, 0.f, 0.f);
    float3 pc = rv;                 // p_k (registers)
    float3 ap;                      // Ap_k (registers)
    float3 Sr, Sp;                  // neighbor sums of r_k, p_k (registers)
    fast_bar(P.bar, ++ep);

    // ---------- CG: one barrier per iteration, 1-array sc1 gather ----------
    for (int k = 0; k < NCG; ++k) {
      if (k == 0) {
        float sx = 0.f, sy = 0.f, sz = 0.f;  // sum r0[u]
#pragma unroll 4
        for (int a = rbeg; a < rend; ++a) {
          const float4 qu = ld_dev((const float4*)((const char*)qRd + P.adj_off[a] + b16));
          sx += qu.x; sy += qu.y; sz += qu.z;
        }
        Sr = make_float3(sx, sy, sz);
        Sp = Sr;  // p0 = r0
        ap.x = (m_v + degf) * pc.x - Sp.x;
        ap.y = (m_v + degf) * pc.y - Sp.y;
        ap.z = (m_v + degf) * pc.z - Sp.z;
      } else {
        // gather S_q = sum Ap_{k-1}[u]; then tiny Gd reduce
        float sx = 0.f, sy = 0.f, sz = 0.f;
#pragma unroll 4
        for (int a = rbeg; a < rend; ++a) {
          const float4 qu = ld_dev((const float4*)((const char*)qRd + P.adj_off[a] + b16));
          sx += qu.x; sy += qu.y; sz += qu.z;
        }
        reduce_small(P.Gd, (pub + 1) & 1, lds_part, lds_acc);  // (pub-1)&1
        const double rsx = lds_acc[b];        // |r_{k-1}|^2 (exact)
        const double pq  = lds_acc[32 + b];   // p.Ap
        const double qq  = lds_acc[64 + b];   // Ap.Ap
        const float alpha = (float)(rsx / (pq + 1e-12));
        const double rs_rec = (double)alpha * (double)alpha * qq - rsx;
        const float beta = (float)(rs_rec / (rsx + 1e-12));
        xacc.x += alpha * pc.x; xacc.y += alpha * pc.y; xacc.z += alpha * pc.z;
        rv.x -= alpha * ap.x; rv.y -= alpha * ap.y; rv.z -= alpha * ap.z;
        Sr.x -= alpha * sx; Sr.y -= alpha * sy; Sr.z -= alpha * sz;
        pc.x = rv.x + beta * pc.x; pc.y = rv.y + beta * pc.y; pc.z = rv.z + beta * pc.z;
        Sp.x = Sr.x + beta * Sp.x; Sp.y = Sr.y + beta * Sp.y; Sp.z = Sr.z + beta * Sp.z;
        ap.x = (m_v + degf) * pc.x - Sp.x;
        ap.y = (m_v + degf) * pc.y - Sp.y;
        ap.z = (m_v + degf) * pc.z - Sp.z;
      }
      st_dev(&qWr[vb], f4(ap));
      publish_store(P.Pd, pub & 1,
                    (double)(rv.x * rv.x) + (double)(rv.y * rv.y) + (double)(rv.z * rv.z),
                    (double)(pc.x * ap.x) + (double)(pc.y * ap.y) + (double)(pc.z * ap.z),
                    (double)(ap.x * ap.x) + (double)(ap.y * ap.y) + (double)(ap.z * ap.z),
                    lds_red);
      fast_bar_red(P.bar, ++ep, P.Pd, P.Gd, pub & 1, &lds_flag);
      ++pub;
      float4* t = qRd; qRd = qWr; qWr = t;
    }

    // ---------- W: final alpha, integrate, write out ----------
    {
      reduce_small(P.Gd, (pub + 1) & 1, lds_part, lds_acc);
      const double rsx = lds_acc[b];
      const double pq  = lds_acc[32 + b];
      const float alpha = (float)(rsx / (pq + 1e-12));
      xacc.x += alpha * pc.x; xacc.y += alpha * pc.y; xacc.z += alpha * pc.z;
      vv = xacc;
      pv.x += DT * vv.x; pv.y += DT * vv.y; pv.z += DT * vv.z;
      st_dev(&P.pos[vb], f4(pv));
      float* o = P.out + ((size_t)(b * NSUB + s) * NVERT + (size_t)v) * 3;
      o[0] = pv.x; o[1] = pv.y; o[2] = pv.z;  // plain: flushed at kernel end
      fast_bar(P.bar, ++ep);
    }
  }
}

extern "C" void kernel_launch(void* const* d_in, const int* in_sizes, int n_in,
                              void* d_out, int out_size, void* d_ws, size_t ws_size,
                              hipStream_t stream) {
  Params P;
  P.action = (const float*)d_in[0];
  P.pos0 = (const float*)d_in[1];
  P.vel0 = (const float*)d_in[2];
  P.rest_len = (const float*)d_in[3];
  P.mass = (const float*)d_in[4];
  P.edge_i = (const int*)d_in[5];
  P.edge_j = (const int*)d_in[6];
  P.out = (float*)d_out;

  char* w = (char*)d_ws;
  auto alloc = [&](size_t bytes) {
    char* p = w;
    w += (bytes + 255) & ~(size_t)255;
    return p;
  };
  const size_t vec_bytes = (size_t)NVERT * 32 * sizeof(float4);  // 4 MB
  P.pos = (float4*)alloc(vec_bytes);
  P.Q0  = (float4*)alloc(vec_bytes);
  P.Q1  = (float4*)alloc(vec_bytes);
  P.rest_eff = (float*)alloc((size_t)NEDGE * 32 * sizeof(float));
  P.adj_off  = (int*)alloc((size_t)2 * NEDGE * sizeof(int));
  P.adjE_off = (int*)alloc((size_t)2 * NEDGE * sizeof(int));
  P.row_ptr  = (int*)alloc((size_t)(NVERT + 1) * sizeof(int));
  P.cursor   = (int*)alloc((size_t)NVERT * sizeof(int));
  P.Pd       = (double*)alloc((size_t)2 * 256 * 96 * sizeof(double));
  P.Gd       = (double*)alloc((size_t)2 * NGRP * 96 * sizeof(double));
  P.bar      = (unsigned*)alloc((size_t)(2 * NGRP + 1) * 32 * sizeof(unsigned));

  void* args[] = { &P };
  hipLaunchCooperativeKernel(reinterpret_cast<void*>(mass_spring_kernel),
                             dim3(GRID), dim3(BLOCK), args, 0, stream);
}

// Round 11
// 2122.140 us; speedup vs baseline: 6.1268x; 1.1334x over previous
//
#include <hip/hip_runtime.h>
#include <hip/hip_cooperative_groups.h>
#include <math.h>

namespace cg = cooperative_groups;

#define NVERT 8192
#define NEDGE 65536
#define NSUB 8
#define NCG 20
#define GRID 256
#define BLOCK 1024
#define DT 0.01f
#define KS 10000.0f
#define NGRP 16   // barrier groups
#define GSIZE 16  // blocks per group (NGRP*GSIZE == GRID)
// 256x1024: the empirically valid cooperative geometry (512x512 never launches).
//
// R10 fix: Gd broadcast coverage. NGRP*96 = 1536 entries but BLOCK = 1024 —
// R8/R9 only loaded entries [0,1024), summing stale LDS for [1024,1536)
// (R8 survived by luck: all 3 dots lose the same blocks -> alpha still ~right;
// R9's stale region held NaN garbage). Now tid loads entry tid AND tid<512
// loads 1024+tid: full coverage, exact dots.
// Carried from R9: xyz-split exchange (float2+float planes, -25% gather
// bytes), Gd load pipelined under the gather.

struct Params {
  const float* action;   // [B][NE]
  const float* pos0;     // [B][NV][3]
  const float* vel0;     // [B][NV][3]
  const float* rest_len; // [NE]
  const float* mass;     // [NV]
  const int* edge_i;     // [NE]
  const int* edge_j;     // [NE]
  float* out;            // [B][NSUB][NV][3]
  float2* posXY;         // [NV*32] exchanged (sc1)
  float*  posZ;          // [NV*32]
  float2 *QXY0, *QXY1;   // ping-pong Ap / r0 staging (sc1)
  float  *QZ0,  *QZ1;
  float* rest_eff;       // [NE][32]  read-only after setup (cached)
  int* adj_off;          // [2NE] neighbor xy-plane byte offset (u*256), cached
  int* adjE_off;         // [2NE] edge byte offset (e*128), cached
  int* row_ptr;          // [NV+1]
  int* cursor;           // [NV]
  double* Pd;            // [2 parity][256 block][96 q] per-block partials (sc1)
  double* Gd;            // [2 parity][NGRP group][96 q] group partials (sc1)
  unsigned* bar;         // [(2*NGRP+1)*32] uints: grp cnts | root | releases
};

union U64F2 { unsigned long long u; float2 f; };
union U32F  { unsigned u; float f; };
union U64D  { unsigned long long u; double d; };

__device__ __forceinline__ float2 ld2_dev(const float2* p) {
  U64F2 r;
  r.u = __hip_atomic_load((const unsigned long long*)p, __ATOMIC_RELAXED, __HIP_MEMORY_SCOPE_AGENT);
  return r.f;
}
__device__ __forceinline__ void st2_dev(float2* p, float2 v) {
  U64F2 r; r.f = v;
  __hip_atomic_store((unsigned long long*)p, r.u, __ATOMIC_RELAXED, __HIP_MEMORY_SCOPE_AGENT);
}
__device__ __forceinline__ float ldf_dev(const float* p) {
  U32F r;
  r.u = __hip_atomic_load((const unsigned*)p, __ATOMIC_RELAXED, __HIP_MEMORY_SCOPE_AGENT);
  return r.f;
}
__device__ __forceinline__ void stf_dev(float* p, float v) {
  U32F r; r.f = v;
  __hip_atomic_store((unsigned*)p, r.u, __ATOMIC_RELAXED, __HIP_MEMORY_SCOPE_AGENT);
}
__device__ __forceinline__ double lddbl_dev(const double* p) {
  U64D r;
  r.u = __hip_atomic_load((const unsigned long long*)p, __ATOMIC_RELAXED, __HIP_MEMORY_SCOPE_AGENT);
  return r.d;
}
__device__ __forceinline__ void stdbl_dev(double* p, double v) {
  U64D r; r.d = v;
  __hip_atomic_store((unsigned long long*)p, r.u, __ATOMIC_RELAXED, __HIP_MEMORY_SCOPE_AGENT);
}

// Plain hierarchical fence-free barrier (for F/W phases: no dots published).
__device__ __forceinline__ void fast_bar(unsigned* bar, unsigned ep) {
  __syncthreads();
  if (threadIdx.x == 0) {
    const unsigned g = blockIdx.x >> 4;
    const unsigned old = __hip_atomic_fetch_add(bar + g * 32, 1u,
                          __ATOMIC_RELAXED, __HIP_MEMORY_SCOPE_AGENT);
    if (old == GSIZE * ep - 1) {
      const unsigned old2 = __hip_atomic_fetch_add(bar + NGRP * 32, 1u,
                             __ATOMIC_RELAXED, __HIP_MEMORY_SCOPE_AGENT);
      if (old2 == NGRP * ep - 1) {
#pragma unroll
        for (int i = 0; i < NGRP; ++i)
          __hip_atomic_store(bar + (NGRP + 1 + i) * 32, ep,
                             __ATOMIC_RELAXED, __HIP_MEMORY_SCOPE_AGENT);
      }
    }
    while (__hip_atomic_load(bar + (NGRP + 1 + g) * 32,
                             __ATOMIC_RELAXED, __HIP_MEMORY_SCOPE_AGENT) < ep)
      __builtin_amdgcn_s_sleep(1);
  }
  __syncthreads();
}

// Barrier WITH in-shadow group reduction (R8-validated).
__device__ __forceinline__ void fast_bar_red(unsigned* bar, unsigned ep,
                                             const double* Pd, double* Gd, int par,
                                             int* lflag) {
  __syncthreads();  // drains this block's Pd sc1 stores; joins all waves
  const unsigned g = blockIdx.x >> 4;
  if (threadIdx.x == 0) {
    const unsigned old = __hip_atomic_fetch_add(bar + g * 32, 1u,
                          __ATOMIC_RELAXED, __HIP_MEMORY_SCOPE_AGENT);
    *lflag = (old == GSIZE * ep - 1);
  }
  __syncthreads();
  if (*lflag) {  // uniform within block: group-last arriver
    if (threadIdx.x < 96) {
      const double* base = Pd + (size_t)par * 256 * 96 + (size_t)(g * GSIZE) * 96
                           + threadIdx.x;
      double s = 0.0;
#pragma unroll
      for (int j = 0; j < GSIZE; ++j) s += lddbl_dev(base + j * 96);
      stdbl_dev(&Gd[(size_t)par * NGRP * 96 + g * 96 + threadIdx.x], s);
    }
    __syncthreads();  // drain Gd stores before root arrival
    if (threadIdx.x == 0) {
      const unsigned old2 = __hip_atomic_fetch_add(bar + NGRP * 32, 1u,
                             __ATOMIC_RELAXED, __HIP_MEMORY_SCOPE_AGENT);
      if (old2 == NGRP * ep - 1) {
#pragma unroll
        for (int i = 0; i < NGRP; ++i)
          __hip_atomic_store(bar + (NGRP + 1 + i) * 32, ep,
                             __ATOMIC_RELAXED, __HIP_MEMORY_SCOPE_AGENT);
      }
    }
  }
  if (threadIdx.x == 0) {
    while (__hip_atomic_load(bar + (NGRP + 1 + g) * 32,
                             __ATOMIC_RELAXED, __HIP_MEMORY_SCOPE_AGENT) < ep)
      __builtin_amdgcn_s_sleep(1);
  }
  __syncthreads();
}

// Publish block partial of 3 per-batch doubles -> Pd[par][blk][0..95].
// No trailing __syncthreads — MUST be followed by fast_bar_red.
__device__ __forceinline__ void publish_store(double* Pd, int par, double d0, double d1,
                                              double d2, double* lds) {
  d0 += __shfl_down(d0, 32);  // lane L += L+32: same batch, paired vertex
  d1 += __shfl_down(d1, 32);
  d2 += __shfl_down(d2, 32);
  const int lane = threadIdx.x & 63, w = threadIdx.x >> 6;
  if (lane < 32) {
    lds[w * 96 + lane] = d0;
    lds[w * 96 + 32 + lane] = d1;
    lds[w * 96 + 64 + lane] = d2;
  }
  __syncthreads();
  if (threadIdx.x < 96) {
    double s = 0.0;
#pragma unroll
    for (int ww = 0; ww < BLOCK / 64; ++ww) s += lds[ww * 96 + threadIdx.x];
    stdbl_dev(&Pd[(size_t)par * 256 * 96 + (size_t)blockIdx.x * 96 + threadIdx.x], s);
  }
}

// Consumer (W phase): read ALL 1536 Gd entries -> lds_acc[q]. Deterministic.
__device__ __forceinline__ void reduce_small(const double* Gd, int par,
                                             double* lds_part, double* lds_acc) {
  const int tid = threadIdx.x;
  const double* base = Gd + (size_t)par * NGRP * 96;
  lds_part[tid] = lddbl_dev(base + tid);                      // [0,1024)
  if (tid < NGRP * 96 - BLOCK)
    lds_part[BLOCK + tid] = lddbl_dev(base + BLOCK + tid);    // [1024,1536)
  __syncthreads();
  if (tid < 96) {
    double s = 0.0;
#pragma unroll
    for (int g = 0; g < NGRP; ++g) s += lds_part[g * 96 + tid];
    lds_acc[tid] = s;
  }
  __syncthreads();
}

__global__ void __launch_bounds__(BLOCK) mass_spring_kernel(Params P) {
  cg::grid_group grid = cg::this_grid();
  __shared__ double lds_red[(BLOCK / 64) * 96];  // 12 KB
  __shared__ double lds_part[NGRP * 96];         // 12 KB
  __shared__ double lds_acc[96];                 // 768 B
  __shared__ int lds_scan[BLOCK];                // 4 KB
  __shared__ int lds_flag;

  const int tid = threadIdx.x;
  const int gtid = blockIdx.x * BLOCK + tid;
  const int b = tid & 31;
  const int v = gtid >> 5;
  const int vb = v * 32 + b;
  const int b8 = b * 8, b4 = b * 4;
  unsigned ep = 0;

  // ---------- setup (real grid.syncs publish plain writes) ----------
  for (int i = gtid; i < NEDGE * 32; i += GRID * BLOCK) {
    const int e = i >> 5, bb = i & 31;
    P.rest_eff[e * 32 + bb] = P.rest_len[e] * (1.0f + P.action[bb * NEDGE + e]);
  }
  float3 pv, vv;
  pv.x = P.pos0[(b * NVERT + v) * 3 + 0];
  pv.y = P.pos0[(b * NVERT + v) * 3 + 1];
  pv.z = P.pos0[(b * NVERT + v) * 3 + 2];
  vv.x = P.vel0[(b * NVERT + v) * 3 + 0];
  vv.y = P.vel0[(b * NVERT + v) * 3 + 1];
  vv.z = P.vel0[(b * NVERT + v) * 3 + 2];
  st2_dev(&P.posXY[vb], make_float2(pv.x, pv.y));
  stf_dev(&P.posZ[vb], pv.z);
  if (gtid < NVERT) P.cursor[gtid] = 0;
  if (gtid < (2 * NGRP + 1) * 32) P.bar[gtid] = 0u;
  grid.sync();

  if (gtid < NEDGE) {
    atomicAdd(&P.cursor[P.edge_i[gtid]], 1);
    atomicAdd(&P.cursor[P.edge_j[gtid]], 1);
  }
  grid.sync();

  if (blockIdx.x == 0) {  // exclusive scan of degrees, 8 per thread
    const int base = tid * (NVERT / BLOCK);
    int loc[NVERT / BLOCK];
    int sum = 0;
#pragma unroll
    for (int i = 0; i < NVERT / BLOCK; ++i) { loc[i] = P.cursor[base + i]; sum += loc[i]; }
    lds_scan[tid] = sum;
    __syncthreads();
    for (int off = 1; off < BLOCK; off <<= 1) {
      int t = 0;
      if (tid >= off) t = lds_scan[tid - off];
      __syncthreads();
      if (tid >= off) lds_scan[tid] += t;
      __syncthreads();
    }
    int run = lds_scan[tid] - sum;
#pragma unroll
    for (int i = 0; i < NVERT / BLOCK; ++i) {
      P.row_ptr[base + i] = run;
      P.cursor[base + i] = run;
      run += loc[i];
    }
    if (tid == BLOCK - 1) P.row_ptr[NVERT] = run;
  }
  grid.sync();

  if (gtid < NEDGE) {  // adjacency: xy-plane byte offsets (u*256)
    const int ei = P.edge_i[gtid], ej = P.edge_j[gtid];
    const int ai = atomicAdd(&P.cursor[ei], 1);
    P.adj_off[ai] = ej * 256; P.adjE_off[ai] = gtid * 128;
    const int aj = atomicAdd(&P.cursor[ej], 1);
    P.adj_off[aj] = ei * 256; P.adjE_off[aj] = gtid * 128;
  }
  grid.sync();  // adjacency/rest_eff/row_ptr now published everywhere

  const float m_v = P.mass[v];
  const int rbeg = P.row_ptr[v], rend = P.row_ptr[v + 1];
  const float degf = (float)(rend - rbeg);

  float2* qXYrd = P.QXY0; float2* qXYwr = P.QXY1;
  float*  qZrd  = P.QZ0;  float*  qZwr  = P.QZ1;
  int pub = 0;  // publish counter; parity = pub & 1

  for (int s = 0; s < NSUB; ++s) {
    // ---------- F: spring force; stage r0 into q planes ----------
    float fx = 0.f, fy = 0.f, fz = 0.f;
#pragma unroll 4
    for (int a = rbeg; a < rend; ++a) {
      const int off = P.adj_off[a];  // u*256
      const float2 pxy = ld2_dev((const float2*)((const char*)P.posXY + off + b8));
      const float  puz = ldf_dev((const float*)((const char*)P.posZ + (off >> 1) + b4));
      const float re = *(const float*)((const char*)P.rest_eff + P.adjE_off[a] + b4);
      const float dx = pv.x - pxy.x, dy = pv.y - pxy.y, dz = pv.z - puz;
      const float l = sqrtf(dx * dx + dy * dy + dz * dz);
      const float coef = -KS * (l - re) / fmaxf(l, 1e-6f);
      fx += coef * dx; fy += coef * dy; fz += coef * dz;
    }
    float3 rv;
    rv.x = m_v * vv.x + DT * fx;
    rv.y = m_v * vv.y + DT * (fy - 9.8f * m_v);
    rv.z = m_v * vv.z + DT * fz;
    st2_dev(&qXYrd[vb], make_float2(rv.x, rv.y));
    stf_dev(&qZrd[vb], rv.z);
    float3 xacc = make_float3(0.f, 0.f, 0.f);
    float3 pc = rv;                 // p_k (registers)
    float3 ap;                      // Ap_k (registers)
    float3 Sr, Sp;                  // neighbor sums of r_k, p_k (registers)
    fast_bar(P.bar, ++ep);

    // ---------- CG: one barrier per iteration, split-plane sc1 gather -------
    for (int k = 0; k < NCG; ++k) {
      if (k == 0) {
        float sx = 0.f, sy = 0.f, sz = 0.f;  // sum r0[u]
#pragma unroll 4
        for (int a = rbeg; a < rend; ++a) {
          const int off = P.adj_off[a];
          const float2 qxy = ld2_dev((const float2*)((const char*)qXYrd + off + b8));
          const float  qz  = ldf_dev((const float*)((const char*)qZrd + (off >> 1) + b4));
          sx += qxy.x; sy += qxy.y; sz += qz;
        }
        Sr = make_float3(sx, sy, sz);
        Sp = Sr;  // p0 = r0
        ap.x = (m_v + degf) * pc.x - Sp.x;
        ap.y = (m_v + degf) * pc.y - Sp.y;
        ap.z = (m_v + degf) * pc.z - Sp.z;
      } else {
        // pipeline: issue FULL-COVERAGE Gd broadcast loads first (1536 entries
        // over 1024 threads: tid and, for tid<512, 1024+tid), park in regs
        const double* gbase = P.Gd + (size_t)((pub + 1) & 1) * NGRP * 96;
        const double gval0 = lddbl_dev(gbase + tid);
        double gval1 = 0.0;
        if (tid < NGRP * 96 - BLOCK) gval1 = lddbl_dev(gbase + BLOCK + tid);
        // gather S_q = sum Ap_{k-1}[u] (hides the Gd latency)
        float sx = 0.f, sy = 0.f, sz = 0.f;
#pragma unroll 4
        for (int a = rbeg; a < rend; ++a) {
          const int off = P.adj_off[a];
          const float2 qxy = ld2_dev((const float2*)((const char*)qXYrd + off + b8));
          const float  qz  = ldf_dev((const float*)((const char*)qZrd + (off >> 1) + b4));
          sx += qxy.x; sy += qxy.y; sz += qz;
        }
        // finish the broadcast reduce in LDS (full 1536 coverage)
        lds_part[tid] = gval0;
        if (tid < NGRP * 96 - BLOCK) lds_part[BLOCK + tid] = gval1;
        __syncthreads();
        if (tid < 96) {
          double s = 0.0;
#pragma unroll
          for (int g = 0; g < NGRP; ++g) s += lds_part[g * 96 + tid];
          lds_acc[tid] = s;
        }
        __syncthreads();
        const double rsx = lds_acc[b];        // |r_{k-1}|^2 (exact)
        const double pq  = lds_acc[32 + b];   // p.Ap
        const double qq  = lds_acc[64 + b];   // Ap.Ap
        const float alpha = (float)(rsx / (pq + 1e-12));
        const double rs_rec = (double)alpha * (double)alpha * qq - rsx;
        const float beta = (float)(rs_rec / (rsx + 1e-12));
        xacc.x += alpha * pc.x; xacc.y += alpha * pc.y; xacc.z += alpha * pc.z;
        rv.x -= alpha * ap.x; rv.y -= alpha * ap.y; rv.z -= alpha * ap.z;
        Sr.x -= alpha * sx; Sr.y -= alpha * sy; Sr.z -= alpha * sz;
        pc.x = rv.x + beta * pc.x; pc.y = rv.y + beta * pc.y; pc.z = rv.z + beta * pc.z;
        Sp.x = Sr.x + beta * Sp.x; Sp.y = Sr.y + beta * Sp.y; Sp.z = Sr.z + beta * Sp.z;
        ap.x = (m_v + degf) * pc.x - Sp.x;
        ap.y = (m_v + degf) * pc.y - Sp.y;
        ap.z = (m_v + degf) * pc.z - Sp.z;
      }
      st2_dev(&qXYwr[vb], make_float2(ap.x, ap.y));
      stf_dev(&qZwr[vb], ap.z);
      publish_store(P.Pd, pub & 1,
                    (double)(rv.x * rv.x) + (double)(rv.y * rv.y) + (double)(rv.z * rv.z),
                    (double)(pc.x * ap.x) + (double)(pc.y * ap.y) + (double)(pc.z * ap.z),
                    (double)(ap.x * ap.x) + (double)(ap.y * ap.y) + (double)(ap.z * ap.z),
                    lds_red);
      fast_bar_red(P.bar, ++ep, P.Pd, P.Gd, pub & 1, &lds_flag);
      ++pub;
      float2* t2 = qXYrd; qXYrd = qXYwr; qXYwr = t2;
      float*  t1 = qZrd;  qZrd  = qZwr;  qZwr  = t1;
    }

    // ---------- W: final alpha, integrate, write out ----------
    {
      reduce_small(P.Gd, (pub + 1) & 1, lds_part, lds_acc);
      const double rsx = lds_acc[b];
      const double pq  = lds_acc[32 + b];
      const float alpha = (float)(rsx / (pq + 1e-12));
      xacc.x += alpha * pc.x; xacc.y += alpha * pc.y; xacc.z += alpha * pc.z;
      vv = xacc;
      pv.x += DT * vv.x; pv.y += DT * vv.y; pv.z += DT * vv.z;
      st2_dev(&P.posXY[vb], make_float2(pv.x, pv.y));
      stf_dev(&P.posZ[vb], pv.z);
      float* o = P.out + ((size_t)(b * NSUB + s) * NVERT + (size_t)v) * 3;
      o[0] = pv.x; o[1] = pv.y; o[2] = pv.z;  // plain: flushed at kernel end
      fast_bar(P.bar, ++ep);
    }
  }
}

extern "C" void kernel_launch(void* const* d_in, const int* in_sizes, int n_in,
                              void* d_out, int out_size, void* d_ws, size_t ws_size,
                              hipStream_t stream) {
  Params P;
  P.action = (const float*)d_in[0];
  P.pos0 = (const float*)d_in[1];
  P.vel0 = (const float*)d_in[2];
  P.rest_len = (const float*)d_in[3];
  P.mass = (const float*)d_in[4];
  P.edge_i = (const int*)d_in[5];
  P.edge_j = (const int*)d_in[6];
  P.out = (float*)d_out;

  char* w = (char*)d_ws;
  auto alloc = [&](size_t bytes) {
    char* p = w;
    w += (bytes + 255) & ~(size_t)255;
    return p;
  };
  const size_t xy_bytes = (size_t)NVERT * 32 * sizeof(float2);  // 2 MB
  const size_t z_bytes  = (size_t)NVERT * 32 * sizeof(float);   // 1 MB
  P.posXY = (float2*)alloc(xy_bytes);
  P.posZ  = (float*)alloc(z_bytes);
  P.QXY0  = (float2*)alloc(xy_bytes);
  P.QXY1  = (float2*)alloc(xy_bytes);
  P.QZ0   = (float*)alloc(z_bytes);
  P.QZ1   = (float*)alloc(z_bytes);
  P.rest_eff = (float*)alloc((size_t)NEDGE * 32 * sizeof(float));
  P.adj_off  = (int*)alloc((size_t)2 * NEDGE * sizeof(int));
  P.adjE_off = (int*)alloc((size_t)2 * NEDGE * sizeof(int));
  P.row_ptr  = (int*)alloc((size_t)(NVERT + 1) * sizeof(int));
  P.cursor   = (int*)alloc((size_t)NVERT * sizeof(int));
  P.Pd       = (double*)alloc((size_t)2 * 256 * 96 * sizeof(double));
  P.Gd       = (double*)alloc((size_t)2 * NGRP * 96 * sizeof(double));
  P.bar      = (unsigned*)alloc((size_t)(2 * NGRP + 1) * 32 * sizeof(unsigned));

  void* args[] = { &P };
  hipLaunchCooperativeKernel(reinterpret_cast<void*>(mass_spring_kernel),
                             dim3(GRID), dim3(BLOCK), args, 0, stream);
}

// Round 12
// 2109.158 us; speedup vs baseline: 6.1645x; 1.0062x over previous
//
#include <hip/hip_runtime.h>
#include <hip/hip_cooperative_groups.h>
#include <math.h>

namespace cg = cooperative_groups;

#define NVERT 8192
#define NEDGE 65536
#define NSUB 8
#define NCG 20
#define GRID 256
#define BLOCK 1024
#define DT 0.01f
#define KS 10000.0f
#define NGRP 16   // barrier groups
#define GSIZE 16  // blocks per group (NGRP*GSIZE == GRID)
#define LDSADJ 1024  // LDS-staged adjacency entries per block (mean ~512)
// 256x1024: the empirically valid cooperative geometry (512x512 never launches).
//
// R11: shorten the gather critical path. (a) Each block's CSR slice is
// contiguous -> stage adj_off in LDS once (ds_read ~20cyc vs L1 ~50+ on the
// dependent chain, frees L1/TA slots for payload); block-uniform fallback if
// slice > 1024. (b) unroll 8 on CG gathers (VGPR headroom to 128).
// Numerics untouched -> absmax must stay exactly 0.0078125.

struct Params {
  const float* action;   // [B][NE]
  const float* pos0;     // [B][NV][3]
  const float* vel0;     // [B][NV][3]
  const float* rest_len; // [NE]
  const float* mass;     // [NV]
  const int* edge_i;     // [NE]
  const int* edge_j;     // [NE]
  float* out;            // [B][NSUB][NV][3]
  float2* posXY;         // [NV*32] exchanged (sc1)
  float*  posZ;          // [NV*32]
  float2 *QXY0, *QXY1;   // ping-pong Ap / r0 staging (sc1)
  float  *QZ0,  *QZ1;
  float* rest_eff;       // [NE][32]  read-only after setup (cached)
  int* adj_off;          // [2NE] neighbor xy-plane byte offset (u*256), cached
  int* adjE_off;         // [2NE] edge byte offset (e*128), cached
  int* row_ptr;          // [NV+1]
  int* cursor;           // [NV]
  double* Pd;            // [2 parity][256 block][96 q] per-block partials (sc1)
  double* Gd;            // [2 parity][NGRP group][96 q] group partials (sc1)
  unsigned* bar;         // [(2*NGRP+1)*32] uints: grp cnts | root | releases
};

union U64F2 { unsigned long long u; float2 f; };
union U32F  { unsigned u; float f; };
union U64D  { unsigned long long u; double d; };

__device__ __forceinline__ float2 ld2_dev(const float2* p) {
  U64F2 r;
  r.u = __hip_atomic_load((const unsigned long long*)p, __ATOMIC_RELAXED, __HIP_MEMORY_SCOPE_AGENT);
  return r.f;
}
__device__ __forceinline__ void st2_dev(float2* p, float2 v) {
  U64F2 r; r.f = v;
  __hip_atomic_store((unsigned long long*)p, r.u, __ATOMIC_RELAXED, __HIP_MEMORY_SCOPE_AGENT);
}
__device__ __forceinline__ float ldf_dev(const float* p) {
  U32F r;
  r.u = __hip_atomic_load((const unsigned*)p, __ATOMIC_RELAXED, __HIP_MEMORY_SCOPE_AGENT);
  return r.f;
}
__device__ __forceinline__ void stf_dev(float* p, float v) {
  U32F r; r.f = v;
  __hip_atomic_store((unsigned*)p, r.u, __ATOMIC_RELAXED, __HIP_MEMORY_SCOPE_AGENT);
}
__device__ __forceinline__ double lddbl_dev(const double* p) {
  U64D r;
  r.u = __hip_atomic_load((const unsigned long long*)p, __ATOMIC_RELAXED, __HIP_MEMORY_SCOPE_AGENT);
  return r.d;
}
__device__ __forceinline__ void stdbl_dev(double* p, double v) {
  U64D r; r.d = v;
  __hip_atomic_store((unsigned long long*)p, r.u, __ATOMIC_RELAXED, __HIP_MEMORY_SCOPE_AGENT);
}

// CG gather: sum the (xy,z) planes over the vertex's neighbors.
// USE_LDS: adjacency offsets from LDS (block slice) vs global fallback.
template<bool USE_LDS>
__device__ __forceinline__ void gather_sum(const char* xyBase, const char* zBase,
                                           const int* ladj, const int* gadj,
                                           int rbeg, int rend, int rb,
                                           int b8, int b4,
                                           float& sx, float& sy, float& sz) {
  sx = 0.f; sy = 0.f; sz = 0.f;
#pragma unroll 8
  for (int a = rbeg; a < rend; ++a) {
    const int off = USE_LDS ? ladj[a - rb] : gadj[a];
    const float2 qxy = ld2_dev((const float2*)(xyBase + off + b8));
    const float  qz  = ldf_dev((const float*)(zBase + (off >> 1) + b4));
    sx += qxy.x; sy += qxy.y; sz += qz;
  }
}

// Plain hierarchical fence-free barrier (for F/W phases: no dots published).
__device__ __forceinline__ void fast_bar(unsigned* bar, unsigned ep) {
  __syncthreads();
  if (threadIdx.x == 0) {
    const unsigned g = blockIdx.x >> 4;
    const unsigned old = __hip_atomic_fetch_add(bar + g * 32, 1u,
                          __ATOMIC_RELAXED, __HIP_MEMORY_SCOPE_AGENT);
    if (old == GSIZE * ep - 1) {
      const unsigned old2 = __hip_atomic_fetch_add(bar + NGRP * 32, 1u,
                             __ATOMIC_RELAXED, __HIP_MEMORY_SCOPE_AGENT);
      if (old2 == NGRP * ep - 1) {
#pragma unroll
        for (int i = 0; i < NGRP; ++i)
          __hip_atomic_store(bar + (NGRP + 1 + i) * 32, ep,
                             __ATOMIC_RELAXED, __HIP_MEMORY_SCOPE_AGENT);
      }
    }
    while (__hip_atomic_load(bar + (NGRP + 1 + g) * 32,
                             __ATOMIC_RELAXED, __HIP_MEMORY_SCOPE_AGENT) < ep)
      __builtin_amdgcn_s_sleep(1);
  }
  __syncthreads();
}

// Barrier WITH in-shadow group reduction (R8-validated).
__device__ __forceinline__ void fast_bar_red(unsigned* bar, unsigned ep,
                                             const double* Pd, double* Gd, int par,
                                             int* lflag) {
  __syncthreads();  // drains this block's Pd sc1 stores; joins all waves
  const unsigned g = blockIdx.x >> 4;
  if (threadIdx.x == 0) {
    const unsigned old = __hip_atomic_fetch_add(bar + g * 32, 1u,
                          __ATOMIC_RELAXED, __HIP_MEMORY_SCOPE_AGENT);
    *lflag = (old == GSIZE * ep - 1);
  }
  __syncthreads();
  if (*lflag) {  // uniform within block: group-last arriver
    if (threadIdx.x < 96) {
      const double* base = Pd + (size_t)par * 256 * 96 + (size_t)(g * GSIZE) * 96
                           + threadIdx.x;
      double s = 0.0;
#pragma unroll
      for (int j = 0; j < GSIZE; ++j) s += lddbl_dev(base + j * 96);
      stdbl_dev(&Gd[(size_t)par * NGRP * 96 + g * 96 + threadIdx.x], s);
    }
    __syncthreads();  // drain Gd stores before root arrival
    if (threadIdx.x == 0) {
      const unsigned old2 = __hip_atomic_fetch_add(bar + NGRP * 32, 1u,
                             __ATOMIC_RELAXED, __HIP_MEMORY_SCOPE_AGENT);
      if (old2 == NGRP * ep - 1) {
#pragma unroll
        for (int i = 0; i < NGRP; ++i)
          __hip_atomic_store(bar + (NGRP + 1 + i) * 32, ep,
                             __ATOMIC_RELAXED, __HIP_MEMORY_SCOPE_AGENT);
      }
    }
  }
  if (threadIdx.x == 0) {
    while (__hip_atomic_load(bar + (NGRP + 1 + g) * 32,
                             __ATOMIC_RELAXED, __HIP_MEMORY_SCOPE_AGENT) < ep)
      __builtin_amdgcn_s_sleep(1);
  }
  __syncthreads();
}

// Publish block partial of 3 per-batch doubles -> Pd[par][blk][0..95].
// No trailing __syncthreads — MUST be followed by fast_bar_red.
__device__ __forceinline__ void publish_store(double* Pd, int par, double d0, double d1,
                                              double d2, double* lds) {
  d0 += __shfl_down(d0, 32);  // lane L += L+32: same batch, paired vertex
  d1 += __shfl_down(d1, 32);
  d2 += __shfl_down(d2, 32);
  const int lane = threadIdx.x & 63, w = threadIdx.x >> 6;
  if (lane < 32) {
    lds[w * 96 + lane] = d0;
    lds[w * 96 + 32 + lane] = d1;
    lds[w * 96 + 64 + lane] = d2;
  }
  __syncthreads();
  if (threadIdx.x < 96) {
    double s = 0.0;
#pragma unroll
    for (int ww = 0; ww < BLOCK / 64; ++ww) s += lds[ww * 96 + threadIdx.x];
    stdbl_dev(&Pd[(size_t)par * 256 * 96 + (size_t)blockIdx.x * 96 + threadIdx.x], s);
  }
}

// Consumer (W phase): read ALL 1536 Gd entries -> lds_acc[q]. Deterministic.
__device__ __forceinline__ void reduce_small(const double* Gd, int par,
                                             double* lds_part, double* lds_acc) {
  const int tid = threadIdx.x;
  const double* base = Gd + (size_t)par * NGRP * 96;
  lds_part[tid] = lddbl_dev(base + tid);                      // [0,1024)
  if (tid < NGRP * 96 - BLOCK)
    lds_part[BLOCK + tid] = lddbl_dev(base + BLOCK + tid);    // [1024,1536)
  __syncthreads();
  if (tid < 96) {
    double s = 0.0;
#pragma unroll
    for (int g = 0; g < NGRP; ++g) s += lds_part[g * 96 + tid];
    lds_acc[tid] = s;
  }
  __syncthreads();
}

__global__ void __launch_bounds__(BLOCK) mass_spring_kernel(Params P) {
  cg::grid_group grid = cg::this_grid();
  __shared__ double lds_red[(BLOCK / 64) * 96];  // 12 KB
  __shared__ double lds_part[NGRP * 96];         // 12 KB
  __shared__ double lds_acc[96];                 // 768 B
  __shared__ int lds_scan[BLOCK];                // 4 KB
  __shared__ int lds_adj[LDSADJ];                // 4 KB: block's CSR adj slice
  __shared__ int lds_flag;

  const int tid = threadIdx.x;
  const int gtid = blockIdx.x * BLOCK + tid;
  const int b = tid & 31;
  const int v = gtid >> 5;
  const int vb = v * 32 + b;
  const int b8 = b * 8, b4 = b * 4;
  unsigned ep = 0;

  // ---------- setup (real grid.syncs publish plain writes) ----------
  for (int i = gtid; i < NEDGE * 32; i += GRID * BLOCK) {
    const int e = i >> 5, bb = i & 31;
    P.rest_eff[e * 32 + bb] = P.rest_len[e] * (1.0f + P.action[bb * NEDGE + e]);
  }
  float3 pv, vv;
  pv.x = P.pos0[(b * NVERT + v) * 3 + 0];
  pv.y = P.pos0[(b * NVERT + v) * 3 + 1];
  pv.z = P.pos0[(b * NVERT + v) * 3 + 2];
  vv.x = P.vel0[(b * NVERT + v) * 3 + 0];
  vv.y = P.vel0[(b * NVERT + v) * 3 + 1];
  vv.z = P.vel0[(b * NVERT + v) * 3 + 2];
  st2_dev(&P.posXY[vb], make_float2(pv.x, pv.y));
  stf_dev(&P.posZ[vb], pv.z);
  if (gtid < NVERT) P.cursor[gtid] = 0;
  if (gtid < (2 * NGRP + 1) * 32) P.bar[gtid] = 0u;
  grid.sync();

  if (gtid < NEDGE) {
    atomicAdd(&P.cursor[P.edge_i[gtid]], 1);
    atomicAdd(&P.cursor[P.edge_j[gtid]], 1);
  }
  grid.sync();

  if (blockIdx.x == 0) {  // exclusive scan of degrees, 8 per thread
    const int base = tid * (NVERT / BLOCK);
    int loc[NVERT / BLOCK];
    int sum = 0;
#pragma unroll
    for (int i = 0; i < NVERT / BLOCK; ++i) { loc[i] = P.cursor[base + i]; sum += loc[i]; }
    lds_scan[tid] = sum;
    __syncthreads();
    for (int off = 1; off < BLOCK; off <<= 1) {
      int t = 0;
      if (tid >= off) t = lds_scan[tid - off];
      __syncthreads();
      if (tid >= off) lds_scan[tid] += t;
      __syncthreads();
    }
    int run = lds_scan[tid] - sum;
#pragma unroll
    for (int i = 0; i < NVERT / BLOCK; ++i) {
      P.row_ptr[base + i] = run;
      P.cursor[base + i] = run;
      run += loc[i];
    }
    if (tid == BLOCK - 1) P.row_ptr[NVERT] = run;
  }
  grid.sync();

  if (gtid < NEDGE) {  // adjacency: xy-plane byte offsets (u*256)
    const int ei = P.edge_i[gtid], ej = P.edge_j[gtid];
    const int ai = atomicAdd(&P.cursor[ei], 1);
    P.adj_off[ai] = ej * 256; P.adjE_off[ai] = gtid * 128;
    const int aj = atomicAdd(&P.cursor[ej], 1);
    P.adj_off[aj] = ei * 256; P.adjE_off[aj] = gtid * 128;
  }
  grid.sync();  // adjacency/rest_eff/row_ptr now published everywhere

  const float m_v = P.mass[v];
  const int rbeg = P.row_ptr[v], rend = P.row_ptr[v + 1];
  const float degf = (float)(rend - rbeg);

  // Stage this block's contiguous CSR adjacency slice into LDS.
  const int rb = P.row_ptr[blockIdx.x * 32];
  const int rcnt = P.row_ptr[blockIdx.x * 32 + 32] - rb;
  const bool useLds = (rcnt <= LDSADJ);
  for (int i = tid; i < rcnt && i < LDSADJ; i += BLOCK)
    lds_adj[i] = P.adj_off[rb + i];
  __syncthreads();

  float2* qXYrd = P.QXY0; float2* qXYwr = P.QXY1;
  float*  qZrd  = P.QZ0;  float*  qZwr  = P.QZ1;
  int pub = 0;  // publish counter; parity = pub & 1

  for (int s = 0; s < NSUB; ++s) {
    // ---------- F: spring force; stage r0 into q planes ----------
    float fx = 0.f, fy = 0.f, fz = 0.f;
#pragma unroll 4
    for (int a = rbeg; a < rend; ++a) {
      const int off = P.adj_off[a];  // u*256
      const float2 pxy = ld2_dev((const float2*)((const char*)P.posXY + off + b8));
      const float  puz = ldf_dev((const float*)((const char*)P.posZ + (off >> 1) + b4));
      const float re = *(const float*)((const char*)P.rest_eff + P.adjE_off[a] + b4);
      const float dx = pv.x - pxy.x, dy = pv.y - pxy.y, dz = pv.z - puz;
      const float l = sqrtf(dx * dx + dy * dy + dz * dz);
      const float coef = -KS * (l - re) / fmaxf(l, 1e-6f);
      fx += coef * dx; fy += coef * dy; fz += coef * dz;
    }
    float3 rv;
    rv.x = m_v * vv.x + DT * fx;
    rv.y = m_v * vv.y + DT * (fy - 9.8f * m_v);
    rv.z = m_v * vv.z + DT * fz;
    st2_dev(&qXYrd[vb], make_float2(rv.x, rv.y));
    stf_dev(&qZrd[vb], rv.z);
    float3 xacc = make_float3(0.f, 0.f, 0.f);
    float3 pc = rv;                 // p_k (registers)
    float3 ap;                      // Ap_k (registers)
    float3 Sr, Sp;                  // neighbor sums of r_k, p_k (registers)
    fast_bar(P.bar, ++ep);

    // ---------- CG: one barrier per iteration, LDS-adj sc1 gather ----------
    for (int k = 0; k < NCG; ++k) {
      if (k == 0) {
        float sx, sy, sz;  // sum r0[u]
        if (useLds)
          gather_sum<true>((const char*)qXYrd, (const char*)qZrd, lds_adj,
                           P.adj_off, rbeg, rend, rb, b8, b4, sx, sy, sz);
        else
          gather_sum<false>((const char*)qXYrd, (const char*)qZrd, lds_adj,
                            P.adj_off, rbeg, rend, rb, b8, b4, sx, sy, sz);
        Sr = make_float3(sx, sy, sz);
        Sp = Sr;  // p0 = r0
        ap.x = (m_v + degf) * pc.x - Sp.x;
        ap.y = (m_v + degf) * pc.y - Sp.y;
        ap.z = (m_v + degf) * pc.z - Sp.z;
      } else {
        // pipeline: issue FULL-COVERAGE Gd broadcast loads first, park in regs
        const double* gbase = P.Gd + (size_t)((pub + 1) & 1) * NGRP * 96;
        const double gval0 = lddbl_dev(gbase + tid);
        double gval1 = 0.0;
        if (tid < NGRP * 96 - BLOCK) gval1 = lddbl_dev(gbase + BLOCK + tid);
        // gather S_q = sum Ap_{k-1}[u] (hides the Gd latency)
        float sx, sy, sz;
        if (useLds)
          gather_sum<true>((const char*)qXYrd, (const char*)qZrd, lds_adj,
                           P.adj_off, rbeg, rend, rb, b8, b4, sx, sy, sz);
        else
          gather_sum<false>((const char*)qXYrd, (const char*)qZrd, lds_adj,
                            P.adj_off, rbeg, rend, rb, b8, b4, sx, sy, sz);
        // finish the broadcast reduce in LDS (full 1536 coverage)
        lds_part[tid] = gval0;
        if (tid < NGRP * 96 - BLOCK) lds_part[BLOCK + tid] = gval1;
        __syncthreads();
        if (tid < 96) {
          double s = 0.0;
#pragma unroll
          for (int g = 0; g < NGRP; ++g) s += lds_part[g * 96 + tid];
          lds_acc[tid] = s;
        }
        __syncthreads();
        const double rsx = lds_acc[b];        // |r_{k-1}|^2 (exact)
        const double pq  = lds_acc[32 + b];   // p.Ap
        const double qq  = lds_acc[64 + b];   // Ap.Ap
        const float alpha = (float)(rsx / (pq + 1e-12));
        const double rs_rec = (double)alpha * (double)alpha * qq - rsx;
        const float beta = (float)(rs_rec / (rsx + 1e-12));
        xacc.x += alpha * pc.x; xacc.y += alpha * pc.y; xacc.z += alpha * pc.z;
        rv.x -= alpha * ap.x; rv.y -= alpha * ap.y; rv.z -= alpha * ap.z;
        Sr.x -= alpha * sx; Sr.y -= alpha * sy; Sr.z -= alpha * sz;
        pc.x = rv.x + beta * pc.x; pc.y = rv.y + beta * pc.y; pc.z = rv.z + beta * pc.z;
        Sp.x = Sr.x + beta * Sp.x; Sp.y = Sr.y + beta * Sp.y; Sp.z = Sr.z + beta * Sp.z;
        ap.x = (m_v + degf) * pc.x - Sp.x;
        ap.y = (m_v + degf) * pc.y - Sp.y;
        ap.z = (m_v + degf) * pc.z - Sp.z;
      }
      st2_dev(&qXYwr[vb], make_float2(ap.x, ap.y));
      stf_dev(&qZwr[vb], ap.z);
      publish_store(P.Pd, pub & 1,
                    (double)(rv.x * rv.x) + (double)(rv.y * rv.y) + (double)(rv.z * rv.z),
                    (double)(pc.x * ap.x) + (double)(pc.y * ap.y) + (double)(pc.z * ap.z),
                    (double)(ap.x * ap.x) + (double)(ap.y * ap.y) + (double)(ap.z * ap.z),
                    lds_red);
      fast_bar_red(P.bar, ++ep, P.Pd, P.Gd, pub & 1, &lds_flag);
      ++pub;
      float2* t2 = qXYrd; qXYrd = qXYwr; qXYwr = t2;
      float*  t1 = qZrd;  qZrd  = qZwr;  qZwr  = t1;
    }

    // ---------- W: final alpha, integrate, write out ----------
    {
      reduce_small(P.Gd, (pub + 1) & 1, lds_part, lds_acc);
      const double rsx = lds_acc[b];
      const double pq  = lds_acc[32 + b];
      const float alpha = (float)(rsx / (pq + 1e-12));
      xacc.x += alpha * pc.x; xacc.y += alpha * pc.y; xacc.z += alpha * pc.z;
      vv = xacc;
      pv.x += DT * vv.x; pv.y += DT * vv.y; pv.z += DT * vv.z;
      st2_dev(&P.posXY[vb], make_float2(pv.x, pv.y));
      stf_dev(&P.posZ[vb], pv.z);
      float* o = P.out + ((size_t)(b * NSUB + s) * NVERT + (size_t)v) * 3;
      o[0] = pv.x; o[1] = pv.y; o[2] = pv.z;  // plain: flushed at kernel end
      fast_bar(P.bar, ++ep);
    }
  }
}

extern "C" void kernel_launch(void* const* d_in, const int* in_sizes, int n_in,
                              void* d_out, int out_size, void* d_ws, size_t ws_size,
                              hipStream_t stream) {
  Params P;
  P.action = (const float*)d_in[0];
  P.pos0 = (const float*)d_in[1];
  P.vel0 = (const float*)d_in[2];
  P.rest_len = (const float*)d_in[3];
  P.mass = (const float*)d_in[4];
  P.edge_i = (const int*)d_in[5];
  P.edge_j = (const int*)d_in[6];
  P.out = (float*)d_out;

  char* w = (char*)d_ws;
  auto alloc = [&](size_t bytes) {
    char* p = w;
    w += (bytes + 255) & ~(size_t)255;
    return p;
  };
  const size_t xy_bytes = (size_t)NVERT * 32 * sizeof(float2);  // 2 MB
  const size_t z_bytes  = (size_t)NVERT * 32 * sizeof(float);   // 1 MB
  P.posXY = (float2*)alloc(xy_bytes);
  P.posZ  = (float*)alloc(z_bytes);
  P.QXY0  = (float2*)alloc(xy_bytes);
  P.QXY1  = (float2*)alloc(xy_bytes);
  P.QZ0   = (float*)alloc(z_bytes);
  P.QZ1   = (float*)alloc(z_bytes);
  P.rest_eff = (float*)alloc((size_t)NEDGE * 32 * sizeof(float));
  P.adj_off  = (int*)alloc((size_t)2 * NEDGE * sizeof(int));
  P.adjE_off = (int*)alloc((size_t)2 * NEDGE * sizeof(int));
  P.row_ptr  = (int*)alloc((size_t)(NVERT + 1) * sizeof(int));
  P.cursor   = (int*)alloc((size_t)NVERT * sizeof(int));
  P.Pd       = (double*)alloc((size_t)2 * 256 * 96 * sizeof(double));
  P.Gd       = (double*)alloc((size_t)2 * NGRP * 96 * sizeof(double));
  P.bar      = (unsigned*)alloc((size_t)(2 * NGRP + 1) * 32 * sizeof(unsigned));

  void* args[] = { &P };
  hipLaunchCooperativeKernel(reinterpret_cast<void*>(mass_spring_kernel),
                             dim3(GRID), dim3(BLOCK), args, 0, stream);
}